// Round 10
// baseline (626.333 us; speedup 1.0000x reference)
//
#include <hip/hip_runtime.h>
#include <math.h>

namespace {

constexpr int NN = 3072;      // nodes
constexpr int NW = 96;        // u32 words per adjacency row (3072 bits)
constexpr int NEDGE_C = 49152;
constexpr int NB = 12;
constexpr float RLN2 = 1.44269504088896340736f;   // 1/ln2

using short8v = __attribute__((ext_vector_type(8))) short;
using f32x4v  = __attribute__((ext_vector_type(4))) float;
typedef unsigned short ushort_t;

__device__ __forceinline__ float leaky02(float x) { return fmaxf(x, 0.2f * x); }
__device__ __forceinline__ float sigm(float x) { return 1.f / (1.f + __expf(-x)); }

// truncation-based bf16 split: hi = trunc(a), lo = a - hi (then trunc again).
__device__ __forceinline__ float hi_part(float a) {
  return __uint_as_float(__float_as_uint(a) & 0xffff0000u);
}
__device__ __forceinline__ unsigned pack_h(float a, float b) {
  return (__float_as_uint(a) >> 16) | (__float_as_uint(b) & 0xffff0000u);
}
__device__ __forceinline__ unsigned pack_l(float a, float b) {
  float ra = a - hi_part(a);
  float rb = b - hi_part(b);
  return (__float_as_uint(ra) >> 16) | (__float_as_uint(rb) & 0xffff0000u);
}

template<int ACT> __device__ __forceinline__ float act_apply(float v) {
  if (ACT == 1) return fmaxf(v, 0.f);
  if (ACT == 2) return v > 0.f ? v : (__expf(v) - 1.f);   // ELU alpha=1
  return v;
}

// ---------------- adjacency ----------------
__global__ __launch_bounds__(256) void k_scatter(const int* __restrict__ ei,
                                                 unsigned* __restrict__ bits) {
  int e = blockIdx.x * 256 + threadIdx.x;
  if (e < NEDGE_C) {
    int s = ei[e];
    int d = ei[NEDGE_C + e];
    atomicOr(&bits[(size_t)d * NW + (s >> 5)], 1u << (s & 31));
  }
}

__global__ __launch_bounds__(128) void k_bmm(const unsigned* __restrict__ a,
                                             const unsigned* __restrict__ src2,
                                             unsigned* __restrict__ outb) {
  __shared__ unsigned row[NW];
  int d = blockIdx.x;
  int t = threadIdx.x;
  if (t < NW) row[t] = a[(size_t)d * NW + t];
  __syncthreads();
  unsigned acc = 0;
  for (int w = 0; w < NW; ++w) {
    unsigned m = row[w];
    while (m) {
      int b = __ffs(m) - 1; m &= m - 1;
      int k = w * 32 + b;
      if (t < NW) acc |= src2[(size_t)k * NW + t];
    }
  }
  if (t < NW) outb[(size_t)d * NW + t] = acc;
}

__global__ __launch_bounds__(256) void k_dinv(const unsigned* __restrict__ bits,
                                              float* __restrict__ dinv) {
  int i = blockIdx.x * 256 + threadIdx.x;
  if (i < NN) {
    int c = 0;
    for (int w = 0; w < NW; ++w) c += __popc(bits[(size_t)i * NW + w]);
    dinv[i] = 1.0f / sqrtf((float)(c + 1));
  }
}

// ---------------- dense GEMM: Y = act(X[M,K] @ W[K,Nc] + b) ----------------
template<int ACT>
__global__ __launch_bounds__(256) void k_gemm(const float* __restrict__ X,
                                              const float* __restrict__ Wm,
                                              const float* __restrict__ bias,
                                              float* __restrict__ Y,
                                              int K, int Nc) {
  __shared__ float Xt[32][68];
  __shared__ float Wt[32][68];
  int R0 = blockIdx.x * 64, C0 = blockIdx.y * 64;
  int t = threadIdx.x;
  int rg = t >> 4, dg = t & 15;
  float acc[4][4] = {{0.f}};
  for (int k0 = 0; k0 < K; k0 += 32) {
    {
      int r = t >> 2, kq = (t & 3) * 8;
      const float* xp = X + (size_t)(R0 + r) * K + k0 + kq;
      float4 a0 = *(const float4*)xp;
      float4 a1 = *(const float4*)(xp + 4);
      Xt[kq + 0][r] = a0.x; Xt[kq + 1][r] = a0.y; Xt[kq + 2][r] = a0.z; Xt[kq + 3][r] = a0.w;
      Xt[kq + 4][r] = a1.x; Xt[kq + 5][r] = a1.y; Xt[kq + 6][r] = a1.z; Xt[kq + 7][r] = a1.w;
      int kk = t >> 3, cq = (t & 7) * 8;
      const float* wp = Wm + (size_t)(k0 + kk) * Nc + C0 + cq;
      *(float4*)&Wt[kk][cq]     = *(const float4*)wp;
      *(float4*)&Wt[kk][cq + 4] = *(const float4*)(wp + 4);
    }
    __syncthreads();
    #pragma unroll 8
    for (int k = 0; k < 32; ++k) {
      float4 av = *(const float4*)&Xt[k][rg * 4];
      float4 bv = *(const float4*)&Wt[k][dg * 4];
      float ar[4] = {av.x, av.y, av.z, av.w};
      float br[4] = {bv.x, bv.y, bv.z, bv.w};
      #pragma unroll
      for (int ri = 0; ri < 4; ++ri)
        #pragma unroll
        for (int ci = 0; ci < 4; ++ci)
          acc[ri][ci] += ar[ri] * br[ci];
    }
    __syncthreads();
  }
  float bv[4] = {0.f, 0.f, 0.f, 0.f};
  if (bias) {
    bv[0] = bias[C0 + dg * 4 + 0]; bv[1] = bias[C0 + dg * 4 + 1];
    bv[2] = bias[C0 + dg * 4 + 2]; bv[3] = bias[C0 + dg * 4 + 3];
  }
  for (int ri = 0; ri < 4; ++ri) {
    int row = R0 + rg * 4 + ri;
    float4 o;
    float* op = (float*)&o;
    #pragma unroll
    for (int ci = 0; ci < 4; ++ci)
      op[ci] = act_apply<ACT>(acc[ri][ci] + bv[ci]);
    *(float4*)&Y[(size_t)row * Nc + C0 + dg * 4] = o;
  }
}

// ---------------- GAT per-node scores (pre-scaled by 1/ln2 -> consumers use exp2) ----------------
template<int H>
__global__ __launch_bounds__(64) void k_scores(const float* __restrict__ h,
                                               const float* __restrict__ as,
                                               const float* __restrict__ ad,
                                               float* __restrict__ es,
                                               float* __restrict__ ed) {
  int i = blockIdx.x, lane = threadIdx.x;
  for (int hh = 0; hh < H; ++hh) {
    float v = h[(size_t)i * (H * 64) + hh * 64 + lane];
    float e1 = v * as[hh * 64 + lane];
    float e2 = v * ad[hh * 64 + lane];
    for (int off = 32; off > 0; off >>= 1) {
      e1 += __shfl_down(e1, off);
      e2 += __shfl_down(e2, off);
    }
    if (lane == 0) {
      es[(size_t)i * H + hh] = e1 * RLN2;
      ed[(size_t)i * H + hh] = e2 * RLN2;
    }
  }
}

__global__ __launch_bounds__(256) void k_gmax8(const float* __restrict__ es,
                                               float* __restrict__ gm) {
  __shared__ float sred[256 * 8];
  int t = threadIdx.x;
  float m[8];
  #pragma unroll
  for (int h = 0; h < 8; ++h) m[h] = -3.0e38f;
  for (int j = t; j < NN; j += 256) {
    float4 e0 = *(const float4*)&es[(size_t)j * 8];
    float4 e1 = *(const float4*)&es[(size_t)j * 8 + 4];
    m[0] = fmaxf(m[0], e0.x); m[1] = fmaxf(m[1], e0.y);
    m[2] = fmaxf(m[2], e0.z); m[3] = fmaxf(m[3], e0.w);
    m[4] = fmaxf(m[4], e1.x); m[5] = fmaxf(m[5], e1.y);
    m[6] = fmaxf(m[6], e1.z); m[7] = fmaxf(m[7], e1.w);
  }
  #pragma unroll
  for (int h = 0; h < 8; ++h) sred[t * 8 + h] = m[h];
  __syncthreads();
  for (int s = 128; s > 0; s >>= 1) {
    if (t < s) {
      #pragma unroll
      for (int h = 0; h < 8; ++h)
        sred[t * 8 + h] = fmaxf(sred[t * 8 + h], sred[(t + s) * 8 + h]);
    }
    __syncthreads();
  }
  if (t < 8) gm[t] = sred[t];
}

__global__ __launch_bounds__(256) void k_gmax1b(const float* __restrict__ es,
                                                float* __restrict__ gm) {
  __shared__ float red[256];
  int t = threadIdx.x;
  const float* e = es + (size_t)blockIdx.x * NN;
  float m = -3.0e38f;
  for (int j = t; j < NN; j += 256) m = fmaxf(m, e[j]);
  red[t] = m;
  __syncthreads();
  for (int s = 128; s > 0; s >>= 1) {
    if (t < s) red[t] = fmaxf(red[t], red[t + s]);
    __syncthreads();
  }
  if (t == 0) gm[blockIdx.x] = red[0];
}

// ---------------- shared-bit enumeration helper ----------------
__device__ __forceinline__ int enum_bits16(const unsigned* rowb, int p,
                                           unsigned* jlist, int* cnt, int t) {
  if (t < 16) {
    int base = 0;
    for (int k = 0; k < t; ++k) base += __popc(rowb[p * 16 + k]);
    unsigned m = rowb[p * 16 + t];
    int j0 = p * 512 + t * 32;
    while (m) { int b = __ffs(m) - 1; m &= m - 1; jlist[base++] = j0 + b; }
    if (t == 15) *cnt = base;
  }
  __syncthreads();
  return *cnt;
}

// ---------------- sparse GAT conv H=8, j-slab partial version ----------------
template<int JS>
__global__ __launch_bounds__(256) void k_gat_sparse8_part(
    const float* __restrict__ hsrc,
    const float* __restrict__ es,
    const float* __restrict__ ed,
    const float* __restrict__ gm,
    const unsigned* __restrict__ bits,
    float* __restrict__ pacc,
    float* __restrict__ pden) {
  constexpr int WPS = NW / JS;
  constexpr int WPP = WPS / 2;
  __shared__ unsigned rowb[WPS];
  __shared__ unsigned jlist[WPP * 32];
  __shared__ float wl[WPP * 32 * 8];
  __shared__ int cnt;
  __shared__ float red[256];
  int i = blockIdx.x, z = blockIdx.y, t = threadIdx.x;
  int w0 = z * WPS;
  if (t < WPS) {
    unsigned wv_ = bits[(size_t)i * NW + w0 + t];
    if (w0 + t == (i >> 5)) wv_ |= 1u << (i & 31);
    rowb[t] = wv_;
  }
  int wv = t >> 6, lane = t & 63;
  int ha = lane >> 4;
  int hb = 4 + (lane >> 4);
  int ca = lane * 4;
  float4 a0 = {0.f, 0.f, 0.f, 0.f};
  float4 a1 = {0.f, 0.f, 0.f, 0.f};
  int hw = t & 7;
  float edv = ed[(size_t)i * 8 + hw];
  float mh = leaky02(edv + gm[hw]);
  float dloc = 0.f;
  __syncthreads();

  for (int p = 0; p < 2; ++p) {
    __syncthreads();
    if (t < WPP) {
      int base = 0;
      for (int k = p * WPP; k < p * WPP + t; ++k) base += __popc(rowb[k]);
      unsigned m = rowb[p * WPP + t];
      int j0 = (w0 + p * WPP + t) * 32;
      while (m) { int b = __ffs(m) - 1; m &= m - 1; jlist[base++] = j0 + b; }
      if (t == WPP - 1) cnt = base;
    }
    __syncthreads();
    int c = cnt;
    if (c == 0) continue;
    for (int pidx = t; pidx < c * 8; pidx += 256) {
      int idx = pidx >> 3;
      int j = (int)jlist[idx];
      float w = exp2f(leaky02(edv + es[(size_t)j * 8 + hw]) - mh);
      wl[idx * 8 + hw] = w;
      dloc += w;
    }
    __syncthreads();
    int idx = wv;
    for (; idx + 4 < c; idx += 8) {
      int j0 = (int)jlist[idx], j1 = (int)jlist[idx + 4];
      float w0a = wl[idx * 8 + ha],       w0b = wl[idx * 8 + hb];
      float w1a = wl[(idx + 4) * 8 + ha], w1b = wl[(idx + 4) * 8 + hb];
      float4 u0 = *(const float4*)&hsrc[(size_t)j0 * 512 + ca];
      float4 u1 = *(const float4*)&hsrc[(size_t)j0 * 512 + 256 + ca];
      float4 v0 = *(const float4*)&hsrc[(size_t)j1 * 512 + ca];
      float4 v1 = *(const float4*)&hsrc[(size_t)j1 * 512 + 256 + ca];
      a0.x += w0a * u0.x; a0.y += w0a * u0.y; a0.z += w0a * u0.z; a0.w += w0a * u0.w;
      a1.x += w0b * u1.x; a1.y += w0b * u1.y; a1.z += w0b * u1.z; a1.w += w0b * u1.w;
      a0.x += w1a * v0.x; a0.y += w1a * v0.y; a0.z += w1a * v0.z; a0.w += w1a * v0.w;
      a1.x += w1b * v1.x; a1.y += w1b * v1.y; a1.z += w1b * v1.z; a1.w += w1b * v1.w;
    }
    if (idx < c) {
      int j0 = (int)jlist[idx];
      float w0a = wl[idx * 8 + ha], w0b = wl[idx * 8 + hb];
      float4 u0 = *(const float4*)&hsrc[(size_t)j0 * 512 + ca];
      float4 u1 = *(const float4*)&hsrc[(size_t)j0 * 512 + 256 + ca];
      a0.x += w0a * u0.x; a0.y += w0a * u0.y; a0.z += w0a * u0.z; a0.w += w0a * u0.w;
      a1.x += w0b * u1.x; a1.y += w0b * u1.y; a1.z += w0b * u1.z; a1.w += w0b * u1.w;
    }
  }
  __syncthreads();
  red[t] = dloc;
  float* rbuf = wl;
  *(float4*)&rbuf[wv * 512 + ca] = a0;
  *(float4*)&rbuf[wv * 512 + 256 + ca] = a1;
  __syncthreads();
  if (t < 8) {
    float s = 0.f;
    for (int k = t; k < 256; k += 8) s += red[k];
    pden[((size_t)z * NN + i) * 8 + t] = s;
  }
  __syncthreads();
  int cc0 = 2 * t;
  float s0 = rbuf[cc0] + rbuf[512 + cc0] + rbuf[1024 + cc0] + rbuf[1536 + cc0];
  float s1 = rbuf[cc0 + 1] + rbuf[512 + cc0 + 1] + rbuf[1024 + cc0 + 1] + rbuf[1536 + cc0 + 1];
  float2 o; o.x = s0; o.y = s1;
  *(float2*)&pacc[((size_t)z * NN + i) * 512 + cc0] = o;
}

// ---------------- sparse GAT conv H=8 (direct, fallback) ----------------
template<int ACT>
__global__ __launch_bounds__(256) void k_gat_sparse8(const float* __restrict__ hsrc,
                                                     const float* __restrict__ es,
                                                     const float* __restrict__ ed,
                                                     const float* __restrict__ gm,
                                                     const unsigned* __restrict__ bits,
                                                     const float* __restrict__ bias,
                                                     float* __restrict__ out) {
  __shared__ unsigned rowb[NW];
  __shared__ unsigned jlist[512];
  __shared__ float wl[512 * 8];
  __shared__ int cnt;
  __shared__ float red[256];
  __shared__ float sden[8];
  int i = blockIdx.x, t = threadIdx.x;
  if (t < NW) {
    unsigned wv_ = bits[(size_t)i * NW + t];
    if (t == (i >> 5)) wv_ |= 1u << (i & 31);
    rowb[t] = wv_;
  }
  int wv = t >> 6, lane = t & 63;
  int ha = lane >> 4;
  int hb = 4 + (lane >> 4);
  int ca = lane * 4;
  float4 a0 = {0.f, 0.f, 0.f, 0.f};
  float4 a1 = {0.f, 0.f, 0.f, 0.f};
  int hw = t & 7;
  float edv = ed[(size_t)i * 8 + hw];
  float mh = leaky02(edv + gm[hw]);
  float dloc = 0.f;
  __syncthreads();

  for (int p = 0; p < 6; ++p) {
    __syncthreads();
    int c = enum_bits16(rowb, p, jlist, &cnt, t);
    if (c == 0) continue;
    for (int pidx = t; pidx < c * 8; pidx += 256) {
      int idx = pidx >> 3;
      int j = (int)jlist[idx];
      float w = exp2f(leaky02(edv + es[(size_t)j * 8 + hw]) - mh);
      wl[idx * 8 + hw] = w;
      dloc += w;
    }
    __syncthreads();
    int idx = wv;
    for (; idx + 4 < c; idx += 8) {
      int j0 = (int)jlist[idx], j1 = (int)jlist[idx + 4];
      float w0a = wl[idx * 8 + ha],       w0b = wl[idx * 8 + hb];
      float w1a = wl[(idx + 4) * 8 + ha], w1b = wl[(idx + 4) * 8 + hb];
      float4 u0 = *(const float4*)&hsrc[(size_t)j0 * 512 + ca];
      float4 u1 = *(const float4*)&hsrc[(size_t)j0 * 512 + 256 + ca];
      float4 v0 = *(const float4*)&hsrc[(size_t)j1 * 512 + ca];
      float4 v1 = *(const float4*)&hsrc[(size_t)j1 * 512 + 256 + ca];
      a0.x += w0a * u0.x; a0.y += w0a * u0.y; a0.z += w0a * u0.z; a0.w += w0a * u0.w;
      a1.x += w0b * u1.x; a1.y += w0b * u1.y; a1.z += w0b * u1.z; a1.w += w0b * u1.w;
      a0.x += w1a * v0.x; a0.y += w1a * v0.y; a0.z += w1a * v0.z; a0.w += w1a * v0.w;
      a1.x += w1b * v1.x; a1.y += w1b * v1.y; a1.z += w1b * v1.z; a1.w += w1b * v1.w;
    }
    if (idx < c) {
      int j0 = (int)jlist[idx];
      float w0a = wl[idx * 8 + ha], w0b = wl[idx * 8 + hb];
      float4 u0 = *(const float4*)&hsrc[(size_t)j0 * 512 + ca];
      float4 u1 = *(const float4*)&hsrc[(size_t)j0 * 512 + 256 + ca];
      a0.x += w0a * u0.x; a0.y += w0a * u0.y; a0.z += w0a * u0.z; a0.w += w0a * u0.w;
      a1.x += w0b * u1.x; a1.y += w0b * u1.y; a1.z += w0b * u1.z; a1.w += w0b * u1.w;
    }
  }
  __syncthreads();
  red[t] = dloc;
  float* rbuf = wl;
  *(float4*)&rbuf[wv * 512 + ca] = a0;
  *(float4*)&rbuf[wv * 512 + 256 + ca] = a1;
  __syncthreads();
  if (t < 8) {
    float s = 0.f;
    for (int k = t; k < 256; k += 8) s += red[k];
    sden[t] = s;
  }
  __syncthreads();
  int cc0 = 2 * t, h2 = cc0 >> 6;
  float inv = 1.0f / sden[h2];
  float s0 = rbuf[cc0] + rbuf[512 + cc0] + rbuf[1024 + cc0] + rbuf[1536 + cc0];
  float s1 = rbuf[cc0 + 1] + rbuf[512 + cc0 + 1] + rbuf[1024 + cc0 + 1] + rbuf[1536 + cc0 + 1];
  float2 o;
  o.x = act_apply<ACT>(s0 * inv + bias[cc0]);
  o.y = act_apply<ACT>(s1 * inv + bias[cc0 + 1]);
  *(float2*)&out[(size_t)i * 512 + cc0] = o;
}

// ---------------- sparse GAT conv H=1 ----------------
template<int ACT>
__global__ __launch_bounds__(256) void k_gat_sparse1(const float* __restrict__ hsrc,
                                                     const float* __restrict__ es,
                                                     const float* __restrict__ ed,
                                                     const float* __restrict__ gm,
                                                     const unsigned* __restrict__ bits,
                                                     const float* __restrict__ bias,
                                                     float* __restrict__ out) {
  __shared__ unsigned rowb[NW];
  __shared__ unsigned jlist[512];
  __shared__ float wl[512];
  __shared__ int cnt;
  __shared__ float red[256];
  __shared__ float red2[16 * 64];
  int i = blockIdx.x, t = threadIdx.x;
  if (t < NW) {
    unsigned wv_ = bits[(size_t)i * NW + t];
    if (t == (i >> 5)) wv_ |= 1u << (i & 31);
    rowb[t] = wv_;
  }
  int wv = t >> 6, lane = t & 63;
  int sub = lane >> 4;
  int col4 = (lane & 15) * 4;
  int g = wv * 4 + sub;
  float4 a = {0.f, 0.f, 0.f, 0.f};
  float edv = ed[i];
  float mh = leaky02(edv + gm[0]);
  float dloc = 0.f;
  __syncthreads();

  for (int p = 0; p < 6; ++p) {
    __syncthreads();
    int c = enum_bits16(rowb, p, jlist, &cnt, t);
    if (c == 0) continue;
    for (int idx = t; idx < c; idx += 256) {
      int j = (int)jlist[idx];
      float w = exp2f(leaky02(edv + es[j]) - mh);
      wl[idx] = w;
      dloc += w;
    }
    __syncthreads();
    for (int base = 0; base < c; base += 16) {
      int idx = base + g;
      if (idx < c) {
        int j = (int)jlist[idx];
        float w = wl[idx];
        float4 v = *(const float4*)&hsrc[(size_t)j * 64 + col4];
        a.x += w * v.x; a.y += w * v.y; a.z += w * v.z; a.w += w * v.w;
      }
    }
  }
  __syncthreads();
  red[t] = dloc;
  __syncthreads();
  for (int s = 128; s > 0; s >>= 1) {
    if (t < s) red[t] += red[t + s];
    __syncthreads();
  }
  float inv = 1.0f / red[0];
  *(float4*)&red2[g * 64 + col4] = a;
  __syncthreads();
  if (t < 64) {
    float s = 0.f;
    #pragma unroll
    for (int k = 0; k < 16; ++k) s += red2[k * 64 + t];
    out[(size_t)i * 64 + t] = act_apply<ACT>(s * inv + bias[t]);
  }
}

// ---------------- split (optionally dinv-scaled) fp32 -> bf16 hi/lo transposed [C cols][NN] ----------------
__global__ __launch_bounds__(256) void k_split_xws(const float* __restrict__ xw, int C,
                                                   const float* __restrict__ dinv,
                                                   ushort_t* __restrict__ hT,
                                                   ushort_t* __restrict__ lT) {
  __shared__ float T[64][65];
  int j0 = blockIdx.x * 64, cb0 = blockIdx.y * 64;
  int t = threadIdx.x;
  int cb = (t & 15) * 4, jrow = t >> 4;
  #pragma unroll
  for (int p = 0; p < 4; ++p) {
    int j = jrow + 16 * p;
    float dv = dinv ? dinv[j0 + j] : 1.f;
    float4 v = *(const float4*)&xw[(size_t)(j0 + j) * C + cb0 + cb];
    T[j][cb] = v.x * dv; T[j][cb + 1] = v.y * dv; T[j][cb + 2] = v.z * dv; T[j][cb + 3] = v.w * dv;
  }
  __syncthreads();
  int c = t >> 2, jq = (t & 3) * 16;
  float x[16];
  #pragma unroll
  for (int k = 0; k < 16; ++k) x[k] = T[jq + k][c];
  size_t base = ((size_t)(cb0 + c)) * NN + j0 + jq;
  uint4 u;
  u.x = pack_h(x[0], x[1]);  u.y = pack_h(x[2], x[3]);
  u.z = pack_h(x[4], x[5]);  u.w = pack_h(x[6], x[7]);
  *(uint4*)&hT[base] = u;
  u.x = pack_h(x[8], x[9]);  u.y = pack_h(x[10], x[11]);
  u.z = pack_h(x[12], x[13]); u.w = pack_h(x[14], x[15]);
  *(uint4*)&hT[base + 8] = u;
  u.x = pack_l(x[0], x[1]);  u.y = pack_l(x[2], x[3]);
  u.z = pack_l(x[4], x[5]);  u.w = pack_l(x[6], x[7]);
  *(uint4*)&lT[base] = u;
  u.x = pack_l(x[8], x[9]);  u.y = pack_l(x[10], x[11]);
  u.z = pack_l(x[12], x[13]); u.w = pack_l(x[14], x[15]);
  *(uint4*)&lT[base + 8] = u;
}

// ---------------- dense GAT conv, MFMA split-bf16, 2-barrier pipelined ----------------
// grid (48, H, JS), block 256 (4 waves). Per tile: weights in regs (global es/bits),
// then sync -> store W+B -> prefetch next B -> sync -> MFMA.
template<int H, int JS>
__global__ __launch_bounds__(256) void k_gat_dense_mfma(
    const ushort_t* __restrict__ hhT,   // [H*64 cols][NN] bf16 hi
    const ushort_t* __restrict__ hlT,   // [H*64 cols][NN] bf16 lo
    const float* __restrict__ es,
    const float* __restrict__ ed,
    const float* __restrict__ gm,
    const unsigned* __restrict__ bits,
    float* __restrict__ pacc,
    float* __restrict__ pden) {
  constexpr int CS = H * 64;
  constexpr int TILES = (NN / 32) / JS;
  constexpr int LW = 40;
  __shared__ ushort_t WhS[64 * LW], WlS[64 * LW];
  __shared__ ushort_t BhS[64 * LW], BlS[64 * LW];
  __shared__ float sred[4][64];
  int R0 = blockIdx.x * 64, hh = blockIdx.y, z = blockIdx.z;
  int t = threadIdx.x;
  int rr = t & 63, jr = t >> 6;
  int wid = t >> 6, lane = t & 63;
  int arow = lane & 15, kg = lane >> 4;
  int sc = t >> 2, sjo = (t & 3) * 8;
  const ushort_t* hhp = hhT + ((size_t)hh * 64 + sc) * NN + sjo;
  const ushort_t* hlp = hlT + ((size_t)hh * 64 + sc) * NN + sjo;
  const unsigned* wrow = bits + (size_t)(R0 + rr) * NW;
  f32x4v acc[4];
  #pragma unroll
  for (int nf = 0; nf < 4; ++nf) acc[nf] = (f32x4v){0.f, 0.f, 0.f, 0.f};
  float spart = 0.f;
  float edv = ed[(size_t)(R0 + rr) * H + hh];
  float mh = leaky02(edv + gm[hh]);
  int aoff = (wid * 16 + arow) * LW + kg * 8;
  int jbase = z * TILES * 32;
  uint4 rbh = *(const uint4*)(hhp + jbase);
  uint4 rbl = *(const uint4*)(hlp + jbase);

  for (int tt = 0; tt < TILES; ++tt) {
    int j0 = jbase + tt * 32;
    // weight phase: registers + global (L2-hit) only — overlaps prev MFMA phase
    unsigned wb = wrow[j0 >> 5];
    {
      int sl = (R0 + rr) - j0;
      if (sl >= 0 && sl < 32) wb |= 1u << sl;
    }
    float w[8], wlo[8];
    #pragma unroll
    for (int q = 0; q < 8; ++q) {
      int jj = jr * 8 + q;
      float esv = es[(size_t)(j0 + jj) * H + hh];
      float v = (wb & (1u << jj)) ? exp2f(leaky02(edv + esv) - mh) : 0.f;
      w[q] = v;
      spart += v;
      wlo[q] = v - hi_part(v);
    }
    uint4 uh, ul;
    uh.x = pack_h(w[0], w[1]); uh.y = pack_h(w[2], w[3]);
    uh.z = pack_h(w[4], w[5]); uh.w = pack_h(w[6], w[7]);
    ul.x = pack_h(wlo[0], wlo[1]); ul.y = pack_h(wlo[2], wlo[3]);
    ul.z = pack_h(wlo[4], wlo[5]); ul.w = pack_h(wlo[6], wlo[7]);
    __syncthreads();                       // prev tile's MFMA reads done
    *(uint4*)&BhS[sc * LW + sjo] = rbh;
    *(uint4*)&BlS[sc * LW + sjo] = rbl;
    *(uint4*)&WhS[rr * LW + jr * 8] = uh;
    *(uint4*)&WlS[rr * LW + jr * 8] = ul;
    if (tt + 1 < TILES) {
      rbh = *(const uint4*)(hhp + j0 + 32);
      rbl = *(const uint4*)(hlp + j0 + 32);
    }
    __syncthreads();                       // W/B visible
    short8v Ah = *(const short8v*)&WhS[aoff];
    short8v Al = *(const short8v*)&WlS[aoff];
    #pragma unroll
    for (int nf = 0; nf < 4; ++nf) {
      short8v bh = *(const short8v*)&BhS[(nf * 16 + arow) * LW + kg * 8];
      short8v bl = *(const short8v*)&BlS[(nf * 16 + arow) * LW + kg * 8];
      acc[nf] = __builtin_amdgcn_mfma_f32_16x16x32_bf16(Ah, bh, acc[nf], 0, 0, 0);
      acc[nf] = __builtin_amdgcn_mfma_f32_16x16x32_bf16(Ah, bl, acc[nf], 0, 0, 0);
      acc[nf] = __builtin_amdgcn_mfma_f32_16x16x32_bf16(Al, bh, acc[nf], 0, 0, 0);
    }
  }
  sred[jr][rr] = spart;
  __syncthreads();
  if (t < 64)
    pden[((size_t)z * NN + R0 + t) * H + hh] =
        sred[0][t] + sred[1][t] + sred[2][t] + sred[3][t];
  #pragma unroll
  for (int nf = 0; nf < 4; ++nf) {
    #pragma unroll
    for (int r = 0; r < 4; ++r) {
      int row = R0 + wid * 16 + kg * 4 + r;
      int c = hh * 64 + nf * 16 + arow;
      pacc[((size_t)z * NN + row) * CS + c] = acc[nf][r];
    }
  }
}

template<int H, int ACT, int JS>
__global__ __launch_bounds__(256) void k_gat_dense_red(const float* __restrict__ pacc,
                                                       const float* __restrict__ pden,
                                                       const float* __restrict__ bias,
                                                       float* __restrict__ out) {
  constexpr int CS = H * 64;
  int idx = blockIdx.x * 256 + threadIdx.x;
  if (idx >= NN * CS) return;
  int row = idx / CS, c = idx - row * CS, hh = c >> 6;
  float a = 0.f, d = 0.f;
  #pragma unroll
  for (int z = 0; z < JS; ++z) a += pacc[((size_t)z * NN + row) * CS + c];
  #pragma unroll
  for (int z = 0; z < JS; ++z) d += pden[((size_t)z * NN + row) * H + hh];
  out[idx] = act_apply<ACT>(a / d + bias[c]);
}

// ---------------- dense GAT direct fp32 (ws fallback) ----------------
template<int H, int ACT>
__global__ __launch_bounds__(256) void k_gat_dense(const float* __restrict__ hsrc,
                                                   const float* __restrict__ es,
                                                   const float* __restrict__ ed,
                                                   const float* __restrict__ gm,
                                                   const unsigned* __restrict__ bits,
                                                   const float* __restrict__ bias,
                                                   float* __restrict__ out) {
  constexpr int CS = H * 64;
  __shared__ float htile[32][68];
  __shared__ float wl[32][68];
  __shared__ float est[32];
  __shared__ unsigned mword[64];
  __shared__ float edl[64], ml[64];
  __shared__ float sred[4][64];
  int R0 = blockIdx.x * 64;
  int hh = blockIdx.y;
  int t = threadIdx.x;
  int rg = t >> 4, dg = t & 15;
  int rr = t & 63, jr = t >> 6;
  float acc[4][4] = {{0.f}};
  float spart = 0.f;
  if (t < 64) {
    float e = ed[(size_t)(R0 + t) * H + hh];
    edl[t] = e;
    ml[t] = leaky02(e + gm[hh]);
  }
  __syncthreads();
  for (int tile = 0; tile < NN / 32; ++tile) {
    int j0 = tile * 32;
    {
      int jj = t >> 3, cq = (t & 7) * 8;
      const float* hp = hsrc + (size_t)(j0 + jj) * CS + hh * 64 + cq;
      *(float4*)&htile[jj][cq]     = *(const float4*)hp;
      *(float4*)&htile[jj][cq + 4] = *(const float4*)(hp + 4);
    }
    if (t < 32) est[t] = es[(size_t)(j0 + t) * H + hh];
    if (t >= 64 && t < 128) mword[t - 64] = bits[(size_t)(R0 + t - 64) * NW + tile];
    __syncthreads();
    {
      unsigned wbits = mword[rr];
      int selfj = (R0 + rr) - j0;
      if (selfj >= 0 && selfj < 32) wbits |= (1u << selfj);
      float edv = edl[rr], mv = ml[rr];
      #pragma unroll
      for (int q = 0; q < 8; ++q) {
        int jj = (q << 2) | jr;
        float w = 0.f;
        if (wbits & (1u << jj)) {
          w = exp2f(leaky02(edv + est[jj]) - mv);
        }
        wl[jj][rr] = w;
        spart += w;
      }
    }
    __syncthreads();
    #pragma unroll 8
    for (int jj = 0; jj < 32; ++jj) {
      float4 av = *(const float4*)&wl[jj][rg * 4];
      float4 bv = *(const float4*)&htile[jj][dg * 4];
      float ar[4] = {av.x, av.y, av.z, av.w};
      float br[4] = {bv.x, bv.y, bv.z, bv.w};
      #pragma unroll
      for (int ri = 0; ri < 4; ++ri)
        #pragma unroll
        for (int ci = 0; ci < 4; ++ci)
          acc[ri][ci] += ar[ri] * br[ci];
    }
    __syncthreads();
  }
  sred[jr][rr] = spart;
  __syncthreads();
  if (t < 64) ml[t] = sred[0][t] + sred[1][t] + sred[2][t] + sred[3][t];
  __syncthreads();
  int cbase = hh * 64 + dg * 4;
  float bv0 = bias[cbase], bv1 = bias[cbase + 1], bv2 = bias[cbase + 2], bv3 = bias[cbase + 3];
  for (int ri = 0; ri < 4; ++ri) {
    int r = rg * 4 + ri;
    float inv = 1.0f / ml[r];
    float4 o;
    o.x = act_apply<ACT>(acc[ri][0] * inv + bv0);
    o.y = act_apply<ACT>(acc[ri][1] * inv + bv1);
    o.z = act_apply<ACT>(acc[ri][2] * inv + bv2);
    o.w = act_apply<ACT>(acc[ri][3] * inv + bv3);
    *(float4*)&out[(size_t)(R0 + r) * CS + cbase] = o;
  }
}

// ---------------- GCN via dense masked MFMA ----------------
template<int JS>
__global__ __launch_bounds__(256) void k_gcn_mfma(
    const ushort_t* __restrict__ bhT,
    const ushort_t* __restrict__ blT,
    const unsigned* __restrict__ b0,
    const unsigned* __restrict__ b1,
    float* __restrict__ pacc,
    int zRows, int rowOffY, int colOffY, int cStride) {
  constexpr int TILES = (NN / 32) / JS;
  constexpr int LW = 40;
  __shared__ ushort_t BhS[128 * LW], BlS[128 * LW];
  __shared__ unsigned mword[64];
  int R0 = blockIdx.x * 64, y = blockIdx.y, z = blockIdx.z;
  const unsigned* bits = y ? b1 : b0;
  int t = threadIdx.x;
  int wid = t >> 6, lane = t & 63;
  int arow = lane & 15, kg = lane >> 4;
  int sc = t >> 1, jh = (t & 1) * 16;
  const ushort_t* bhp = bhT + ((size_t)y * 128 + sc) * NN + jh;
  const ushort_t* blp = blT + ((size_t)y * 128 + sc) * NN + jh;
  f32x4v acc[4][2];
  #pragma unroll
  for (int rf = 0; rf < 4; ++rf)
    #pragma unroll
    for (int cf = 0; cf < 2; ++cf) acc[rf][cf] = (f32x4v){0.f, 0.f, 0.f, 0.f};

  for (int tt = 0; tt < TILES; ++tt) {
    int tile = z * TILES + tt, j0 = tile * 32;
    uint4 h0 = *(const uint4*)(bhp + j0);
    uint4 h1 = *(const uint4*)(bhp + j0 + 8);
    uint4 l0 = *(const uint4*)(blp + j0);
    uint4 l1 = *(const uint4*)(blp + j0 + 8);
    __syncthreads();
    *(uint4*)&BhS[sc * LW + jh]     = h0;
    *(uint4*)&BhS[sc * LW + jh + 8] = h1;
    *(uint4*)&BlS[sc * LW + jh]     = l0;
    *(uint4*)&BlS[sc * LW + jh + 8] = l1;
    if (t < 64) mword[t] = bits[(size_t)(R0 + t) * NW + tile];
    __syncthreads();
    short8v Aw[4];
    #pragma unroll
    for (int rf = 0; rf < 4; ++rf) {
      unsigned wb = mword[rf * 16 + arow];
      unsigned oct = (wb >> (kg * 8)) & 0xffu;
      #pragma unroll
      for (int q = 0; q < 8; ++q)
        Aw[rf][q] = (short)(((oct >> q) & 1u) ? 0x3f80 : 0);
    }
    #pragma unroll
    for (int cf = 0; cf < 2; ++cf) {
      int col = wid * 32 + cf * 16 + arow;
      short8v bh = *(const short8v*)&BhS[col * LW + kg * 8];
      short8v bl = *(const short8v*)&BlS[col * LW + kg * 8];
      #pragma unroll
      for (int rf = 0; rf < 4; ++rf) {
        acc[rf][cf] = __builtin_amdgcn_mfma_f32_16x16x32_bf16(Aw[rf], bh, acc[rf][cf], 0, 0, 0);
        acc[rf][cf] = __builtin_amdgcn_mfma_f32_16x16x32_bf16(Aw[rf], bl, acc[rf][cf], 0, 0, 0);
      }
    }
  }
  #pragma unroll
  for (int rf = 0; rf < 4; ++rf)
    #pragma unroll
    for (int cf = 0; cf < 2; ++cf)
      #pragma unroll
      for (int r = 0; r < 4; ++r) {
        int row = R0 + rf * 16 + kg * 4 + r;
        int c = wid * 32 + cf * 16 + arow;
        pacc[((size_t)z * zRows + (size_t)y * rowOffY + row) * cStride + y * colOffY + c] =
            acc[rf][cf][r];
      }
}

template<int JS>
__global__ __launch_bounds__(256) void k_gcn_red(const float* __restrict__ pacc,
                                                 const float* __restrict__ xw,
                                                 const float* __restrict__ d0,
                                                 const float* __restrict__ d1,
                                                 const float* __restrict__ bias,
                                                 float* __restrict__ out,
                                                 int rowsTotal, int C) {
  int idx = blockIdx.x * 256 + threadIdx.x;
  if (idx >= rowsTotal * C) return;
  int blk = idx / C, c = idx - blk * C;
  float s = 0.f;
  #pragma unroll
  for (int z = 0; z < JS; ++z) s += pacc[((size_t)z * rowsTotal + blk) * C + c];
  int i = blk >= NN ? blk - NN : blk;
  float di = (blk >= NN ? d1 : d0)[i];
  float v = di * (s + di * xw[(size_t)blk * C + c]) + bias[c];
  out[idx] = fmaxf(v, 0.f);
}

// ---------------- sparse GCN convs (ws fallback) ----------------
__global__ __launch_bounds__(256) void k_gcn256(const float* __restrict__ xw,
                                                const unsigned* __restrict__ bits,
                                                const float* __restrict__ dinv,
                                                const float* __restrict__ bias,
                                                float* __restrict__ out) {
  __shared__ unsigned rowb[NW];
  __shared__ unsigned jlist[512];
  __shared__ int cnt;
  int i = blockIdx.x, t = threadIdx.x;
  if (t < NW) rowb[t] = bits[(size_t)i * NW + t];
  float acc = 0.f;
  __syncthreads();
  for (int p = 0; p < 6; ++p) {
    __syncthreads();
    int cN = enum_bits16(rowb, p, jlist, &cnt, t);
    for (int idx = 0; idx < cN; ++idx) {
      int j = (int)jlist[idx];
      acc += dinv[j] * xw[(size_t)j * 256 + t];
    }
  }
  float di = dinv[i];
  float v = di * (acc + di * xw[(size_t)i * 256 + t]) + bias[t];
  out[(size_t)i * 256 + t] = fmaxf(v, 0.f);
}

__global__ __launch_bounds__(256) void k_gcn128b(const float* __restrict__ xw,
                                                 const unsigned* __restrict__ b0,
                                                 const unsigned* __restrict__ b1,
                                                 const float* __restrict__ d0,
                                                 const float* __restrict__ d1,
                                                 const float* __restrict__ bias,
                                                 float* __restrict__ outb) {
  __shared__ unsigned rowb[NW];
  __shared__ unsigned jlist[512];
  __shared__ int cnt;
  __shared__ float red[256];
  int blk = blockIdx.x, t = threadIdx.x;
  int br = blk >= NN;
  int i = br ? blk - NN : blk;
  const unsigned* bits = br ? b1 : b0;
  const float* dinv = br ? d1 : d0;
  const float* xb = xw + (size_t)br * NN * 128;
  if (t < NW) rowb[t] = bits[(size_t)i * NW + t];
  int g = t >> 7, c = t & 127;
  float acc = 0.f;
  __syncthreads();
  for (int p = 0; p < 6; ++p) {
    __syncthreads();
    int cN = enum_bits16(rowb, p, jlist, &cnt, t);
    for (int idx = g; idx < cN; idx += 2) {
      int j = (int)jlist[idx];
      acc += dinv[j] * xb[(size_t)j * 128 + c];
    }
  }
  __syncthreads();
  red[t] = acc;
  __syncthreads();
  if (t < 128) {
    acc = red[t] + red[t + 128];
    float di = dinv[i];
    float v = di * (acc + di * xb[(size_t)i * 128 + c]) + bias[c];
    outb[(size_t)blk * 128 + c] = fmaxf(v, 0.f);
  }
}

// ---------------- fusion kernels ----------------
__global__ __launch_bounds__(256) void k_highway(const float* __restrict__ aa,
                                                 const float* __restrict__ bb,
                                                 float* __restrict__ hh) {
  int idx = blockIdx.x * 256 + threadIdx.x;
  if (idx < NN * 64) {
    float a = aa[idx], b = bb[idx];
    float z = sigm(a + b);
    hh[idx] = z * b + (1.f - z) * a;
  }
}

__global__ __launch_bounds__(256) void k_gru(const float* __restrict__ gx,
                                             const float* __restrict__ gh,
                                             const float* __restrict__ hh,
                                             float* __restrict__ cc) {
  int idx = blockIdx.x * 256 + threadIdx.x;
  if (idx < NN * 64) {
    int i = idx >> 6, d = idx & 63;
    float xr = gx[(size_t)i * 192 + d];
    float xz = gx[(size_t)i * 192 + 64 + d];
    float xn = gx[(size_t)i * 192 + 128 + d];
    float hr = gh[(size_t)i * 192 + d];
    float hz = gh[(size_t)i * 192 + 64 + d];
    float hn = gh[(size_t)i * 192 + 128 + d];
    float r = sigm(xr + hr);
    float z = sigm(xz + hz);
    float n = tanhf(xn + r * hn);
    cc[idx] = (1.f - z) * n + z * hh[idx];
  }
}

__global__ __launch_bounds__(64) void k_pool(const float* __restrict__ cc,
                                             const int* __restrict__ atoms,
                                             const int* __restrict__ resl,
                                             float* __restrict__ vi) {
  int s = blockIdx.x, lane = threadIdx.x;
  int start = 0;
  for (int k = 0; k < s; ++k) start += atoms[k] + resl[k];
  int end = start + atoms[s] + resl[s];
  if (end > NN) end = NN;
  float m = -3.0e38f;
  for (int r = start; r < end; ++r) m = fmaxf(m, cc[(size_t)r * 64 + lane]);
  vi[s * 64 + lane] = m;
}

__global__ __launch_bounds__(256) void k_final(const float* __restrict__ vi,
                                               const float* __restrict__ tAW,
                                               const float* __restrict__ tAb,
                                               const float* __restrict__ tBW,
                                               const float* __restrict__ tBb,
                                               float* __restrict__ out) {
  __shared__ float v[NB * 64];
  __shared__ float t1[NB * 128];
  int t = threadIdx.x;
  for (int idx = t; idx < NB * 64; idx += 256) v[idx] = vi[idx];
  __syncthreads();
  for (int idx = t; idx < NB * 128; idx += 256) {
    int r = idx >> 7, c = idx & 127;
    float a = tAb[c];
    for (int k = 0; k < 64; ++k) a += v[r * 64 + k] * tAW[k * 128 + c];
    t1[idx] = fmaxf(a, 0.f);
  }
  __syncthreads();
  for (int idx = t; idx < NB * 120; idx += 256) {
    int r = idx / 120, c = idx % 120;
    float a = tBb[c];
    for (int k = 0; k < 128; ++k) a += t1[r * 128 + k] * tBW[k * 120 + c];
    out[idx] = a;
  }
}

} // anonymous namespace

extern "C" void kernel_launch(void* const* d_in, const int* in_sizes, int n_in,
                              void* d_out, int out_size, void* d_ws, size_t ws_size,
                              hipStream_t stream) {
  (void)in_sizes; (void)n_in; (void)out_size;
  const float* x     = (const float*)d_in[0];
  const float* g1_W  = (const float*)d_in[2];
  const float* g1_as = (const float*)d_in[3];
  const float* g1_ad = (const float*)d_in[4];
  const float* g1_b  = (const float*)d_in[5];
  const float* g2_W  = (const float*)d_in[6];
  const float* g2_as = (const float*)d_in[7];
  const float* g2_ad = (const float*)d_in[8];
  const float* g2_b  = (const float*)d_in[9];
  const float* gA_W  = (const float*)d_in[10];
  const float* gA_b  = (const float*)d_in[11];
  const float* gB_W  = (const float*)d_in[12];
  const float* gB_b  = (const float*)d_in[13];
  const float* gC_W  = (const float*)d_in[14];
  const float* gC_b  = (const float*)d_in[15];
  const float* c2_W  = (const float*)d_in[16];
  const float* c2_b  = (const float*)d_in[17];
  const float* c3_W  = (const float*)d_in[18];
  const float* c3_b  = (const float*)d_in[19];
  const float* hwA_W = (const float*)d_in[20];
  const float* hwA_b = (const float*)d_in[21];
  const float* hwB_W = (const float*)d_in[22];
  const float* hwB_b = (const float*)d_in[23];
  const float* gWih  = (const float*)d_in[24];
  const float* gWhh  = (const float*)d_in[25];
  const float* gbih  = (const float*)d_in[26];
  const float* gbhh  = (const float*)d_in[27];
  const float* tA_W  = (const float*)d_in[28];
  const float* tA_b  = (const float*)d_in[29];
  const float* tB_W  = (const float*)d_in[30];
  const float* tB_b  = (const float*)d_in[31];
  const int* edges   = (const int*)d_in[32];
  const int* atoms   = (const int*)d_in[33];
  const int* resl    = (const int*)d_in[34];
  float* out = (float*)d_out;

  // ---- workspace carve ----
  unsigned* bitsA  = (unsigned*)d_ws;
  unsigned* bitsA2 = bitsA + (size_t)NN * NW;
  unsigned* bitsA3 = bitsA2 + (size_t)NN * NW;
  float* fp = (float*)(bitsA3 + (size_t)NN * NW);
  float* dinvA  = fp; fp += NN;
  float* dinvA2 = fp; fp += NN;
  float* HB     = fp; fp += (size_t)NN * 512;
  float* ES1    = fp; fp += (size_t)NN * 8;
  float* ED1    = fp; fp += (size_t)NN * 8;
  float* GM1    = fp; fp += 16;
  float* V1ALL  = fp; fp += (size_t)3 * NN * 512;   // GAT1 out, branch-major
  float* H2BALL = fp; fp += (size_t)3 * NN * 64;
  float* ES2ALL = fp; fp += (size_t)3 * NN;
  float* ED2ALL = fp; fp += (size_t)3 * NN;
  float* GM2ALL = fp; fp += 16;
  float* V2ALL  = fp; fp += (size_t)3 * NN * 64;
  float* V3ALL  = fp; fp += (size_t)3 * NN * 64;
  float* V4ALL  = fp; fp += (size_t)3 * NN * 128;
  float* V5ALL  = fp; fp += (size_t)3 * NN * 64;    // branch3 slice = H3F
  float* XC2    = fp; fp += (size_t)2 * NN * 128;
  float* TG     = fp; fp += (size_t)2 * NN * 128;   // GCN1 out (br1: T1, br2: H2F)
  float* XC3    = fp; fp += (size_t)NN * 256;
  float* H1F    = fp; fp += (size_t)NN * 256;
  float* AAb    = fp; fp += (size_t)NN * 64;
  float* BBb    = fp; fp += (size_t)NN * 64;
  float* HHb    = fp; fp += (size_t)NN * 64;
  float* VI     = fp; fp += NB * 64;
  // aliases on V1ALL (dead after the g2 batched gemm)
  float* GX = V1ALL;
  float* GH = V1ALL + (size_t)NN * 192;
  float* CC = V1ALL + (size_t)NN * 384;
  // split-bf16 + partial buffers
  char* cp = (char*)fp;
  ushort_t* HhT8 = (ushort_t*)cp; cp += (size_t)512 * NN * 2;
  ushort_t* HlT8 = (ushort_t*)cp; cp += (size_t)512 * NN * 2;
  ushort_t* HhT1 = (ushort_t*)cp; cp += (size_t)64 * NN * 2;
  ushort_t* HlT1 = (ushort_t*)cp; cp += (size_t)64 * NN * 2;
  ushort_t* XWSH = (ushort_t*)cp; cp += (size_t)256 * NN * 2;
  ushort_t* XWSL = (ushort_t*)cp; cp += (size_t)256 * NN * 2;
  float* PACC = (float*)cp; cp += (size_t)4 * NN * 512 * 4;   // reused by all partial passes
  float* PDEN = (float*)cp; cp += (size_t)16 * NN * 8 * 4;
  int mode = ((size_t)(cp - (char*)d_ws) <= ws_size) ? 1 : 0;

  float* H3F = V5ALL + (size_t)2 * NN * 64;
  float* H2F = TG + (size_t)NN * 128;

  // ---- adjacency ----
  hipMemsetAsync(bitsA, 0, (size_t)NN * NW * sizeof(unsigned), stream);
  k_scatter<<<(NEDGE_C + 255) / 256, 256, 0, stream>>>(edges, bitsA);
  k_bmm<<<NN, 128, 0, stream>>>(bitsA, bitsA, bitsA2);
  k_bmm<<<NN, 128, 0, stream>>>(bitsA, bitsA2, bitsA3);
  k_dinv<<<NN / 256, 256, 0, stream>>>(bitsA, dinvA);
  k_dinv<<<NN / 256, 256, 0, stream>>>(bitsA2, dinvA2);

  // ---- shared GAT1 input ----
  k_gemm<0><<<dim3(48, 8), 256, 0, stream>>>(x, g1_W, nullptr, HB, 64, 512);
  k_scores<8><<<NN, 64, 0, stream>>>(HB, g1_as, g1_ad, ES1, ED1);
  k_gmax8<<<1, 256, 0, stream>>>(ES1, GM1);

  // ---- GAT1 for all 3 branches -> V1ALL ----
  if (mode) {
    k_gat_sparse8_part<4><<<dim3(NN, 4), 256, 0, stream>>>(HB, ES1, ED1, GM1, bitsA, PACC, PDEN);
    k_gat_dense_red<8, 2, 4><<<NN * 512 / 256, 256, 0, stream>>>(PACC, PDEN, g1_b, V1ALL);
    k_gat_sparse8_part<4><<<dim3(NN, 4), 256, 0, stream>>>(HB, ES1, ED1, GM1, bitsA2, PACC, PDEN);
    k_gat_dense_red<8, 2, 4><<<NN * 512 / 256, 256, 0, stream>>>(PACC, PDEN, g1_b, V1ALL + (size_t)NN * 512);
    k_split_xws<<<dim3(48, 8), 256, 0, stream>>>(HB, 512, nullptr, HhT8, HlT8);
    k_gat_dense_mfma<8, 4><<<dim3(48, 8, 4), 256, 0, stream>>>(HhT8, HlT8, ES1, ED1, GM1, bitsA3, PACC, PDEN);
    k_gat_dense_red<8, 2, 4><<<NN * 512 / 256, 256, 0, stream>>>(PACC, PDEN, g1_b, V1ALL + (size_t)2 * NN * 512);
  } else {
    k_gat_sparse8<2><<<NN, 256, 0, stream>>>(HB, ES1, ED1, GM1, bitsA, g1_b, V1ALL);
    k_gat_sparse8<2><<<NN, 256, 0, stream>>>(HB, ES1, ED1, GM1, bitsA2, g1_b, V1ALL + (size_t)NN * 512);
    k_gat_dense<8, 2><<<dim3(48, 8), 256, 0, stream>>>(HB, ES1, ED1, GM1, bitsA3, g1_b, V1ALL + (size_t)2 * NN * 512);
  }

  // ---- batched GAT2 prologue ----
  k_gemm<0><<<dim3(144, 1), 256, 0, stream>>>(V1ALL, g2_W, nullptr, H2BALL, 512, 64);
  k_scores<1><<<3 * NN, 64, 0, stream>>>(H2BALL, g2_as, g2_ad, ES2ALL, ED2ALL);
  k_gmax1b<<<3, 256, 0, stream>>>(ES2ALL, GM2ALL);

  // ---- GAT2 per branch -> V2ALL ----
  k_gat_sparse1<1><<<NN, 256, 0, stream>>>(H2BALL, ES2ALL, ED2ALL, GM2ALL, bitsA, g2_b, V2ALL);
  k_gat_sparse1<1><<<NN, 256, 0, stream>>>(H2BALL + (size_t)NN * 64, ES2ALL + NN, ED2ALL + NN,
                                           GM2ALL + 1, bitsA2, g2_b, V2ALL + (size_t)NN * 64);
  if (mode) {
    k_split_xws<<<dim3(48, 1), 256, 0, stream>>>(H2BALL + (size_t)2 * NN * 64, 64, nullptr, HhT1, HlT1);
    k_gat_dense_mfma<1, 16><<<dim3(48, 1, 16), 256, 0, stream>>>(
        HhT1, HlT1, ES2ALL + 2 * NN, ED2ALL + 2 * NN, GM2ALL + 2, bitsA3, PACC, PDEN);
    k_gat_dense_red<1, 1, 16><<<NN * 64 / 256, 256, 0, stream>>>(PACC, PDEN, g2_b, V2ALL + (size_t)2 * NN * 64);
  } else {
    k_gat_dense<1, 1><<<dim3(48, 1), 256, 0, stream>>>(
        H2BALL + (size_t)2 * NN * 64, ES2ALL + 2 * NN, ED2ALL + 2 * NN, GM2ALL + 2, bitsA3, g2_b,
        V2ALL + (size_t)2 * NN * 64);
  }

  // ---- batched branch tails ----
  k_gemm<1><<<dim3(144, 1), 256, 0, stream>>>(V2ALL, gA_W, gA_b, V3ALL, 64, 64);
  k_gemm<1><<<dim3(144, 2), 256, 0, stream>>>(V3ALL, gB_W, gB_b, V4ALL, 64, 128);
  k_gemm<1><<<dim3(144, 1), 256, 0, stream>>>(V4ALL, gC_W, gC_b, V5ALL, 128, 64);

  // ---- GCN chains (branches 1+2 batched) ----
  k_gemm<0><<<dim3(96, 2), 256, 0, stream>>>(V5ALL, c2_W, nullptr, XC2, 64, 128);
  if (mode) {
    k_split_xws<<<dim3(48, 2), 256, 0, stream>>>(XC2, 128, dinvA, XWSH, XWSL);
    k_split_xws<<<dim3(48, 2), 256, 0, stream>>>(XC2 + (size_t)NN * 128, 128, dinvA2,
                                                 XWSH + (size_t)128 * NN, XWSL + (size_t)128 * NN);
    k_gcn_mfma<8><<<dim3(48, 2, 8), 256, 0, stream>>>(XWSH, XWSL, bitsA, bitsA2, PACC, 2 * NN, NN, 0, 128);
    k_gcn_red<8><<<2 * NN * 128 / 256, 256, 0, stream>>>(PACC, XC2, dinvA, dinvA2, c2_b, TG, 2 * NN, 128);
  } else {
    k_gcn128b<<<2 * NN, 256, 0, stream>>>(XC2, bitsA, bitsA2, dinvA, dinvA2, c2_b, TG);
  }
  k_gemm<0><<<dim3(48, 4), 256, 0, stream>>>(TG, c3_W, nullptr, XC3, 128, 256);
  if (mode) {
    k_split_xws<<<dim3(48, 4), 256, 0, stream>>>(XC3, 256, dinvA, XWSH, XWSL);
    k_gcn_mfma<8><<<dim3(48, 2, 8), 256, 0, stream>>>(XWSH, XWSL, bitsA, bitsA, PACC, NN, 0, 128, 256);
    k_gcn_red<8><<<NN * 256 / 256, 256, 0, stream>>>(PACC, XC3, dinvA, dinvA, c3_b, H1F, NN, 256);
  } else {
    k_gcn256<<<NN, 256, 0, stream>>>(XC3, bitsA, dinvA, c3_b, H1F);
  }

  // ---- highway + GRU + pool + head ----
  k_gemm<0><<<dim3(48, 1), 256, 0, stream>>>(H1F, hwA_W, hwA_b, AAb, 256, 64);
  k_gemm<0><<<dim3(48, 1), 256, 0, stream>>>(H2F, hwB_W, hwB_b, BBb, 128, 64);
  k_highway<<<NN * 64 / 256, 256, 0, stream>>>(AAb, BBb, HHb);
  k_gemm<0><<<dim3(48, 3), 256, 0, stream>>>(H3F, gWih, gbih, GX, 64, 192);
  k_gemm<0><<<dim3(48, 3), 256, 0, stream>>>(HHb, gWhh, gbhh, GH, 64, 192);
  k_gru<<<NN * 64 / 256, 256, 0, stream>>>(GX, GH, HHb, CC);
  k_pool<<<NB, 64, 0, stream>>>(CC, atoms, resl, VI);
  k_final<<<1, 256, 0, stream>>>(VI, tA_W, tA_b, tB_W, tB_b, out);
}

// Round 11
// 585.415 us; speedup vs baseline: 1.0699x; 1.0699x over previous
//
#include <hip/hip_runtime.h>
#include <math.h>

namespace {

constexpr int NN = 3072;      // nodes
constexpr int NW = 96;        // u32 words per adjacency row (3072 bits)
constexpr int NEDGE_C = 49152;
constexpr int NB = 12;
constexpr float RLN2 = 1.44269504088896340736f;   // 1/ln2

using short8v = __attribute__((ext_vector_type(8))) short;
using f32x4v  = __attribute__((ext_vector_type(4))) float;
typedef unsigned short ushort_t;

__device__ __forceinline__ float leaky02(float x) { return fmaxf(x, 0.2f * x); }
__device__ __forceinline__ float sigm(float x) { return 1.f / (1.f + __expf(-x)); }

// truncation-based bf16 split: hi = trunc(a), lo = a - hi (then trunc again).
__device__ __forceinline__ float hi_part(float a) {
  return __uint_as_float(__float_as_uint(a) & 0xffff0000u);
}
__device__ __forceinline__ unsigned pack_h(float a, float b) {
  return (__float_as_uint(a) >> 16) | (__float_as_uint(b) & 0xffff0000u);
}
__device__ __forceinline__ unsigned pack_l(float a, float b) {
  float ra = a - hi_part(a);
  float rb = b - hi_part(b);
  return (__float_as_uint(ra) >> 16) | (__float_as_uint(rb) & 0xffff0000u);
}

template<int ACT> __device__ __forceinline__ float act_apply(float v) {
  if (ACT == 1) return fmaxf(v, 0.f);
  if (ACT == 2) return v > 0.f ? v : (__expf(v) - 1.f);   // ELU alpha=1
  return v;
}

// ---------------- adjacency ----------------
__global__ __launch_bounds__(256) void k_scatter(const int* __restrict__ ei,
                                                 unsigned* __restrict__ bits) {
  int e = blockIdx.x * 256 + threadIdx.x;
  if (e < NEDGE_C) {
    int s = ei[e];
    int d = ei[NEDGE_C + e];
    atomicOr(&bits[(size_t)d * NW + (s >> 5)], 1u << (s & 31));
  }
}

__global__ __launch_bounds__(128) void k_bmm(const unsigned* __restrict__ a,
                                             const unsigned* __restrict__ src2,
                                             unsigned* __restrict__ outb) {
  __shared__ unsigned row[NW];
  int d = blockIdx.x;
  int t = threadIdx.x;
  if (t < NW) row[t] = a[(size_t)d * NW + t];
  __syncthreads();
  unsigned acc = 0;
  for (int w = 0; w < NW; ++w) {
    unsigned m = row[w];
    while (m) {
      int b = __ffs(m) - 1; m &= m - 1;
      int k = w * 32 + b;
      if (t < NW) acc |= src2[(size_t)k * NW + t];
    }
  }
  if (t < NW) outb[(size_t)d * NW + t] = acc;
}

__global__ __launch_bounds__(256) void k_dinv(const unsigned* __restrict__ bits,
                                              float* __restrict__ dinv) {
  int i = blockIdx.x * 256 + threadIdx.x;
  if (i < NN) {
    int c = 0;
    for (int w = 0; w < NW; ++w) c += __popc(bits[(size_t)i * NW + w]);
    dinv[i] = 1.0f / sqrtf((float)(c + 1));
  }
}

// ---------------- dense GEMM: Y = act(X[M,K] @ W[K,Nc] + b) ----------------
template<int ACT>
__global__ __launch_bounds__(256) void k_gemm(const float* __restrict__ X,
                                              const float* __restrict__ Wm,
                                              const float* __restrict__ bias,
                                              float* __restrict__ Y,
                                              int K, int Nc) {
  __shared__ float Xt[32][68];
  __shared__ float Wt[32][68];
  int R0 = blockIdx.x * 64, C0 = blockIdx.y * 64;
  int t = threadIdx.x;
  int rg = t >> 4, dg = t & 15;
  float acc[4][4] = {{0.f}};
  for (int k0 = 0; k0 < K; k0 += 32) {
    {
      int r = t >> 2, kq = (t & 3) * 8;
      const float* xp = X + (size_t)(R0 + r) * K + k0 + kq;
      float4 a0 = *(const float4*)xp;
      float4 a1 = *(const float4*)(xp + 4);
      Xt[kq + 0][r] = a0.x; Xt[kq + 1][r] = a0.y; Xt[kq + 2][r] = a0.z; Xt[kq + 3][r] = a0.w;
      Xt[kq + 4][r] = a1.x; Xt[kq + 5][r] = a1.y; Xt[kq + 6][r] = a1.z; Xt[kq + 7][r] = a1.w;
      int kk = t >> 3, cq = (t & 7) * 8;
      const float* wp = Wm + (size_t)(k0 + kk) * Nc + C0 + cq;
      *(float4*)&Wt[kk][cq]     = *(const float4*)wp;
      *(float4*)&Wt[kk][cq + 4] = *(const float4*)(wp + 4);
    }
    __syncthreads();
    #pragma unroll 8
    for (int k = 0; k < 32; ++k) {
      float4 av = *(const float4*)&Xt[k][rg * 4];
      float4 bv = *(const float4*)&Wt[k][dg * 4];
      float ar[4] = {av.x, av.y, av.z, av.w};
      float br[4] = {bv.x, bv.y, bv.z, bv.w};
      #pragma unroll
      for (int ri = 0; ri < 4; ++ri)
        #pragma unroll
        for (int ci = 0; ci < 4; ++ci)
          acc[ri][ci] += ar[ri] * br[ci];
    }
    __syncthreads();
  }
  float bv[4] = {0.f, 0.f, 0.f, 0.f};
  if (bias) {
    bv[0] = bias[C0 + dg * 4 + 0]; bv[1] = bias[C0 + dg * 4 + 1];
    bv[2] = bias[C0 + dg * 4 + 2]; bv[3] = bias[C0 + dg * 4 + 3];
  }
  for (int ri = 0; ri < 4; ++ri) {
    int row = R0 + rg * 4 + ri;
    float4 o;
    float* op = (float*)&o;
    #pragma unroll
    for (int ci = 0; ci < 4; ++ci)
      op[ci] = act_apply<ACT>(acc[ri][ci] + bv[ci]);
    *(float4*)&Y[(size_t)row * Nc + C0 + dg * 4] = o;
  }
}

// ---------------- GAT per-node scores (pre-scaled by 1/ln2 -> consumers use exp2) ----------------
template<int H>
__global__ __launch_bounds__(64) void k_scores(const float* __restrict__ h,
                                               const float* __restrict__ as,
                                               const float* __restrict__ ad,
                                               float* __restrict__ es,
                                               float* __restrict__ ed) {
  int i = blockIdx.x, lane = threadIdx.x;
  for (int hh = 0; hh < H; ++hh) {
    float v = h[(size_t)i * (H * 64) + hh * 64 + lane];
    float e1 = v * as[hh * 64 + lane];
    float e2 = v * ad[hh * 64 + lane];
    for (int off = 32; off > 0; off >>= 1) {
      e1 += __shfl_down(e1, off);
      e2 += __shfl_down(e2, off);
    }
    if (lane == 0) {
      es[(size_t)i * H + hh] = e1 * RLN2;
      ed[(size_t)i * H + hh] = e2 * RLN2;
    }
  }
}

__global__ __launch_bounds__(256) void k_gmax8(const float* __restrict__ es,
                                               float* __restrict__ gm) {
  __shared__ float sred[256 * 8];
  int t = threadIdx.x;
  float m[8];
  #pragma unroll
  for (int h = 0; h < 8; ++h) m[h] = -3.0e38f;
  for (int j = t; j < NN; j += 256) {
    float4 e0 = *(const float4*)&es[(size_t)j * 8];
    float4 e1 = *(const float4*)&es[(size_t)j * 8 + 4];
    m[0] = fmaxf(m[0], e0.x); m[1] = fmaxf(m[1], e0.y);
    m[2] = fmaxf(m[2], e0.z); m[3] = fmaxf(m[3], e0.w);
    m[4] = fmaxf(m[4], e1.x); m[5] = fmaxf(m[5], e1.y);
    m[6] = fmaxf(m[6], e1.z); m[7] = fmaxf(m[7], e1.w);
  }
  #pragma unroll
  for (int h = 0; h < 8; ++h) sred[t * 8 + h] = m[h];
  __syncthreads();
  for (int s = 128; s > 0; s >>= 1) {
    if (t < s) {
      #pragma unroll
      for (int h = 0; h < 8; ++h)
        sred[t * 8 + h] = fmaxf(sred[t * 8 + h], sred[(t + s) * 8 + h]);
    }
    __syncthreads();
  }
  if (t < 8) gm[t] = sred[t];
}

__global__ __launch_bounds__(256) void k_gmax1b(const float* __restrict__ es,
                                                float* __restrict__ gm) {
  __shared__ float red[256];
  int t = threadIdx.x;
  const float* e = es + (size_t)blockIdx.x * NN;
  float m = -3.0e38f;
  for (int j = t; j < NN; j += 256) m = fmaxf(m, e[j]);
  red[t] = m;
  __syncthreads();
  for (int s = 128; s > 0; s >>= 1) {
    if (t < s) red[t] = fmaxf(red[t], red[t + s]);
    __syncthreads();
  }
  if (t == 0) gm[blockIdx.x] = red[0];
}

// ---------------- shared-bit enumeration helper ----------------
__device__ __forceinline__ int enum_bits16(const unsigned* rowb, int p,
                                           unsigned* jlist, int* cnt, int t) {
  if (t < 16) {
    int base = 0;
    for (int k = 0; k < t; ++k) base += __popc(rowb[p * 16 + k]);
    unsigned m = rowb[p * 16 + t];
    int j0 = p * 512 + t * 32;
    while (m) { int b = __ffs(m) - 1; m &= m - 1; jlist[base++] = j0 + b; }
    if (t == 15) *cnt = base;
  }
  __syncthreads();
  return *cnt;
}

// ---------------- sparse GAT conv H=8, j-slab partial version ----------------
template<int JS>
__global__ __launch_bounds__(256) void k_gat_sparse8_part(
    const float* __restrict__ hsrc,
    const float* __restrict__ es,
    const float* __restrict__ ed,
    const float* __restrict__ gm,
    const unsigned* __restrict__ bits,
    float* __restrict__ pacc,
    float* __restrict__ pden) {
  constexpr int WPS = NW / JS;
  constexpr int WPP = WPS / 2;
  __shared__ unsigned rowb[WPS];
  __shared__ unsigned jlist[WPP * 32];
  __shared__ float wl[WPP * 32 * 8];
  __shared__ int cnt;
  __shared__ float red[256];
  int i = blockIdx.x, z = blockIdx.y, t = threadIdx.x;
  int w0 = z * WPS;
  if (t < WPS) {
    unsigned wv_ = bits[(size_t)i * NW + w0 + t];
    if (w0 + t == (i >> 5)) wv_ |= 1u << (i & 31);
    rowb[t] = wv_;
  }
  int wv = t >> 6, lane = t & 63;
  int ha = lane >> 4;
  int hb = 4 + (lane >> 4);
  int ca = lane * 4;
  float4 a0 = {0.f, 0.f, 0.f, 0.f};
  float4 a1 = {0.f, 0.f, 0.f, 0.f};
  int hw = t & 7;
  float edv = ed[(size_t)i * 8 + hw];
  float mh = leaky02(edv + gm[hw]);
  float dloc = 0.f;
  __syncthreads();

  for (int p = 0; p < 2; ++p) {
    __syncthreads();
    if (t < WPP) {
      int base = 0;
      for (int k = p * WPP; k < p * WPP + t; ++k) base += __popc(rowb[k]);
      unsigned m = rowb[p * WPP + t];
      int j0 = (w0 + p * WPP + t) * 32;
      while (m) { int b = __ffs(m) - 1; m &= m - 1; jlist[base++] = j0 + b; }
      if (t == WPP - 1) cnt = base;
    }
    __syncthreads();
    int c = cnt;
    if (c == 0) continue;
    for (int pidx = t; pidx < c * 8; pidx += 256) {
      int idx = pidx >> 3;
      int j = (int)jlist[idx];
      float w = exp2f(leaky02(edv + es[(size_t)j * 8 + hw]) - mh);
      wl[idx * 8 + hw] = w;
      dloc += w;
    }
    __syncthreads();
    int idx = wv;
    for (; idx + 4 < c; idx += 8) {
      int j0 = (int)jlist[idx], j1 = (int)jlist[idx + 4];
      float w0a = wl[idx * 8 + ha],       w0b = wl[idx * 8 + hb];
      float w1a = wl[(idx + 4) * 8 + ha], w1b = wl[(idx + 4) * 8 + hb];
      float4 u0 = *(const float4*)&hsrc[(size_t)j0 * 512 + ca];
      float4 u1 = *(const float4*)&hsrc[(size_t)j0 * 512 + 256 + ca];
      float4 v0 = *(const float4*)&hsrc[(size_t)j1 * 512 + ca];
      float4 v1 = *(const float4*)&hsrc[(size_t)j1 * 512 + 256 + ca];
      a0.x += w0a * u0.x; a0.y += w0a * u0.y; a0.z += w0a * u0.z; a0.w += w0a * u0.w;
      a1.x += w0b * u1.x; a1.y += w0b * u1.y; a1.z += w0b * u1.z; a1.w += w0b * u1.w;
      a0.x += w1a * v0.x; a0.y += w1a * v0.y; a0.z += w1a * v0.z; a0.w += w1a * v0.w;
      a1.x += w1b * v1.x; a1.y += w1b * v1.y; a1.z += w1b * v1.z; a1.w += w1b * v1.w;
    }
    if (idx < c) {
      int j0 = (int)jlist[idx];
      float w0a = wl[idx * 8 + ha], w0b = wl[idx * 8 + hb];
      float4 u0 = *(const float4*)&hsrc[(size_t)j0 * 512 + ca];
      float4 u1 = *(const float4*)&hsrc[(size_t)j0 * 512 + 256 + ca];
      a0.x += w0a * u0.x; a0.y += w0a * u0.y; a0.z += w0a * u0.z; a0.w += w0a * u0.w;
      a1.x += w0b * u1.x; a1.y += w0b * u1.y; a1.z += w0b * u1.z; a1.w += w0b * u1.w;
    }
  }
  __syncthreads();
  red[t] = dloc;
  float* rbuf = wl;
  *(float4*)&rbuf[wv * 512 + ca] = a0;
  *(float4*)&rbuf[wv * 512 + 256 + ca] = a1;
  __syncthreads();
  if (t < 8) {
    float s = 0.f;
    for (int k = t; k < 256; k += 8) s += red[k];
    pden[((size_t)z * NN + i) * 8 + t] = s;
  }
  __syncthreads();
  int cc0 = 2 * t;
  float s0 = rbuf[cc0] + rbuf[512 + cc0] + rbuf[1024 + cc0] + rbuf[1536 + cc0];
  float s1 = rbuf[cc0 + 1] + rbuf[512 + cc0 + 1] + rbuf[1024 + cc0 + 1] + rbuf[1536 + cc0 + 1];
  float2 o; o.x = s0; o.y = s1;
  *(float2*)&pacc[((size_t)z * NN + i) * 512 + cc0] = o;
}

// ---------------- sparse GAT conv H=8 (direct, fallback) ----------------
template<int ACT>
__global__ __launch_bounds__(256) void k_gat_sparse8(const float* __restrict__ hsrc,
                                                     const float* __restrict__ es,
                                                     const float* __restrict__ ed,
                                                     const float* __restrict__ gm,
                                                     const unsigned* __restrict__ bits,
                                                     const float* __restrict__ bias,
                                                     float* __restrict__ out) {
  __shared__ unsigned rowb[NW];
  __shared__ unsigned jlist[512];
  __shared__ float wl[512 * 8];
  __shared__ int cnt;
  __shared__ float red[256];
  __shared__ float sden[8];
  int i = blockIdx.x, t = threadIdx.x;
  if (t < NW) {
    unsigned wv_ = bits[(size_t)i * NW + t];
    if (t == (i >> 5)) wv_ |= 1u << (i & 31);
    rowb[t] = wv_;
  }
  int wv = t >> 6, lane = t & 63;
  int ha = lane >> 4;
  int hb = 4 + (lane >> 4);
  int ca = lane * 4;
  float4 a0 = {0.f, 0.f, 0.f, 0.f};
  float4 a1 = {0.f, 0.f, 0.f, 0.f};
  int hw = t & 7;
  float edv = ed[(size_t)i * 8 + hw];
  float mh = leaky02(edv + gm[hw]);
  float dloc = 0.f;
  __syncthreads();

  for (int p = 0; p < 6; ++p) {
    __syncthreads();
    int c = enum_bits16(rowb, p, jlist, &cnt, t);
    if (c == 0) continue;
    for (int pidx = t; pidx < c * 8; pidx += 256) {
      int idx = pidx >> 3;
      int j = (int)jlist[idx];
      float w = exp2f(leaky02(edv + es[(size_t)j * 8 + hw]) - mh);
      wl[idx * 8 + hw] = w;
      dloc += w;
    }
    __syncthreads();
    int idx = wv;
    for (; idx + 4 < c; idx += 8) {
      int j0 = (int)jlist[idx], j1 = (int)jlist[idx + 4];
      float w0a = wl[idx * 8 + ha],       w0b = wl[idx * 8 + hb];
      float w1a = wl[(idx + 4) * 8 + ha], w1b = wl[(idx + 4) * 8 + hb];
      float4 u0 = *(const float4*)&hsrc[(size_t)j0 * 512 + ca];
      float4 u1 = *(const float4*)&hsrc[(size_t)j0 * 512 + 256 + ca];
      float4 v0 = *(const float4*)&hsrc[(size_t)j1 * 512 + ca];
      float4 v1 = *(const float4*)&hsrc[(size_t)j1 * 512 + 256 + ca];
      a0.x += w0a * u0.x; a0.y += w0a * u0.y; a0.z += w0a * u0.z; a0.w += w0a * u0.w;
      a1.x += w0b * u1.x; a1.y += w0b * u1.y; a1.z += w0b * u1.z; a1.w += w0b * u1.w;
      a0.x += w1a * v0.x; a0.y += w1a * v0.y; a0.z += w1a * v0.z; a0.w += w1a * v0.w;
      a1.x += w1b * v1.x; a1.y += w1b * v1.y; a1.z += w1b * v1.z; a1.w += w1b * v1.w;
    }
    if (idx < c) {
      int j0 = (int)jlist[idx];
      float w0a = wl[idx * 8 + ha], w0b = wl[idx * 8 + hb];
      float4 u0 = *(const float4*)&hsrc[(size_t)j0 * 512 + ca];
      float4 u1 = *(const float4*)&hsrc[(size_t)j0 * 512 + 256 + ca];
      a0.x += w0a * u0.x; a0.y += w0a * u0.y; a0.z += w0a * u0.z; a0.w += w0a * u0.w;
      a1.x += w0b * u1.x; a1.y += w0b * u1.y; a1.z += w0b * u1.z; a1.w += w0b * u1.w;
    }
  }
  __syncthreads();
  red[t] = dloc;
  float* rbuf = wl;
  *(float4*)&rbuf[wv * 512 + ca] = a0;
  *(float4*)&rbuf[wv * 512 + 256 + ca] = a1;
  __syncthreads();
  if (t < 8) {
    float s = 0.f;
    for (int k = t; k < 256; k += 8) s += red[k];
    sden[t] = s;
  }
  __syncthreads();
  int cc0 = 2 * t, h2 = cc0 >> 6;
  float inv = 1.0f / sden[h2];
  float s0 = rbuf[cc0] + rbuf[512 + cc0] + rbuf[1024 + cc0] + rbuf[1536 + cc0];
  float s1 = rbuf[cc0 + 1] + rbuf[512 + cc0 + 1] + rbuf[1024 + cc0 + 1] + rbuf[1536 + cc0 + 1];
  float2 o;
  o.x = act_apply<ACT>(s0 * inv + bias[cc0]);
  o.y = act_apply<ACT>(s1 * inv + bias[cc0 + 1]);
  *(float2*)&out[(size_t)i * 512 + cc0] = o;
}

// ---------------- sparse GAT conv H=1 ----------------
template<int ACT>
__global__ __launch_bounds__(256) void k_gat_sparse1(const float* __restrict__ hsrc,
                                                     const float* __restrict__ es,
                                                     const float* __restrict__ ed,
                                                     const float* __restrict__ gm,
                                                     const unsigned* __restrict__ bits,
                                                     const float* __restrict__ bias,
                                                     float* __restrict__ out) {
  __shared__ unsigned rowb[NW];
  __shared__ unsigned jlist[512];
  __shared__ float wl[512];
  __shared__ int cnt;
  __shared__ float red[256];
  __shared__ float red2[16 * 64];
  int i = blockIdx.x, t = threadIdx.x;
  if (t < NW) {
    unsigned wv_ = bits[(size_t)i * NW + t];
    if (t == (i >> 5)) wv_ |= 1u << (i & 31);
    rowb[t] = wv_;
  }
  int wv = t >> 6, lane = t & 63;
  int sub = lane >> 4;
  int col4 = (lane & 15) * 4;
  int g = wv * 4 + sub;
  float4 a = {0.f, 0.f, 0.f, 0.f};
  float edv = ed[i];
  float mh = leaky02(edv + gm[0]);
  float dloc = 0.f;
  __syncthreads();

  for (int p = 0; p < 6; ++p) {
    __syncthreads();
    int c = enum_bits16(rowb, p, jlist, &cnt, t);
    if (c == 0) continue;
    for (int idx = t; idx < c; idx += 256) {
      int j = (int)jlist[idx];
      float w = exp2f(leaky02(edv + es[j]) - mh);
      wl[idx] = w;
      dloc += w;
    }
    __syncthreads();
    for (int base = 0; base < c; base += 16) {
      int idx = base + g;
      if (idx < c) {
        int j = (int)jlist[idx];
        float w = wl[idx];
        float4 v = *(const float4*)&hsrc[(size_t)j * 64 + col4];
        a.x += w * v.x; a.y += w * v.y; a.z += w * v.z; a.w += w * v.w;
      }
    }
  }
  __syncthreads();
  red[t] = dloc;
  __syncthreads();
  for (int s = 128; s > 0; s >>= 1) {
    if (t < s) red[t] += red[t + s];
    __syncthreads();
  }
  float inv = 1.0f / red[0];
  *(float4*)&red2[g * 64 + col4] = a;
  __syncthreads();
  if (t < 64) {
    float s = 0.f;
    #pragma unroll
    for (int k = 0; k < 16; ++k) s += red2[k * 64 + t];
    out[(size_t)i * 64 + t] = act_apply<ACT>(s * inv + bias[t]);
  }
}

// ---------------- split (optionally dinv-scaled) fp32 -> bf16 hi/lo transposed [C cols][NN] ----------------
__global__ __launch_bounds__(256) void k_split_xws(const float* __restrict__ xw, int C,
                                                   const float* __restrict__ dinv,
                                                   ushort_t* __restrict__ hT,
                                                   ushort_t* __restrict__ lT) {
  __shared__ float T[64][65];
  int j0 = blockIdx.x * 64, cb0 = blockIdx.y * 64;
  int t = threadIdx.x;
  int cb = (t & 15) * 4, jrow = t >> 4;
  #pragma unroll
  for (int p = 0; p < 4; ++p) {
    int j = jrow + 16 * p;
    float dv = dinv ? dinv[j0 + j] : 1.f;
    float4 v = *(const float4*)&xw[(size_t)(j0 + j) * C + cb0 + cb];
    T[j][cb] = v.x * dv; T[j][cb + 1] = v.y * dv; T[j][cb + 2] = v.z * dv; T[j][cb + 3] = v.w * dv;
  }
  __syncthreads();
  int c = t >> 2, jq = (t & 3) * 16;
  float x[16];
  #pragma unroll
  for (int k = 0; k < 16; ++k) x[k] = T[jq + k][c];
  size_t base = ((size_t)(cb0 + c)) * NN + j0 + jq;
  uint4 u;
  u.x = pack_h(x[0], x[1]);  u.y = pack_h(x[2], x[3]);
  u.z = pack_h(x[4], x[5]);  u.w = pack_h(x[6], x[7]);
  *(uint4*)&hT[base] = u;
  u.x = pack_h(x[8], x[9]);  u.y = pack_h(x[10], x[11]);
  u.z = pack_h(x[12], x[13]); u.w = pack_h(x[14], x[15]);
  *(uint4*)&hT[base + 8] = u;
  u.x = pack_l(x[0], x[1]);  u.y = pack_l(x[2], x[3]);
  u.z = pack_l(x[4], x[5]);  u.w = pack_l(x[6], x[7]);
  *(uint4*)&lT[base] = u;
  u.x = pack_l(x[8], x[9]);  u.y = pack_l(x[10], x[11]);
  u.z = pack_l(x[12], x[13]); u.w = pack_l(x[14], x[15]);
  *(uint4*)&lT[base + 8] = u;
}

// ---------------- dense GAT conv, MFMA split-bf16, j-split partial ----------------
template<int H, int JS>
__global__ __launch_bounds__(256) void k_gat_dense_mfma(
    const ushort_t* __restrict__ hhT,   // [H*64][NN] bf16 hi
    const ushort_t* __restrict__ hlT,   // [H*64][NN] bf16 lo
    const float* __restrict__ es,
    const float* __restrict__ ed,
    const float* __restrict__ gm,
    const unsigned* __restrict__ bits,
    float* __restrict__ pacc,
    float* __restrict__ pden) {
  constexpr int CS = H * 64;
  constexpr int TILES = (NN / 32) / JS;
  constexpr int LW = 40;
  __shared__ ushort_t WhS[64 * LW], WlS[64 * LW];
  __shared__ ushort_t BhS[64 * LW], BlS[64 * LW];
  __shared__ float est[32];
  __shared__ unsigned mword[64];
  __shared__ float edl[64], ml[64];
  __shared__ float sred[4][64];
  int R0 = blockIdx.x * 64, hh = blockIdx.y, z = blockIdx.z;
  int t = threadIdx.x;
  int rr = t & 63, jr = t >> 6;
  int wid = t >> 6, lane = t & 63;
  int arow = lane & 15, kg = lane >> 4;
  int sc = t >> 2, sjo = (t & 3) * 8;
  const ushort_t* hhp = hhT + ((size_t)hh * 64 + sc) * NN + sjo;
  const ushort_t* hlp = hlT + ((size_t)hh * 64 + sc) * NN + sjo;
  f32x4v acc[4];
  #pragma unroll
  for (int nf = 0; nf < 4; ++nf) acc[nf] = (f32x4v){0.f, 0.f, 0.f, 0.f};
  float spart = 0.f;
  if (t < 64) {
    float e = ed[(size_t)(R0 + t) * H + hh];
    edl[t] = e;
    ml[t] = leaky02(e + gm[hh]);
  }
  int aoff = (wid * 16 + arow) * LW + kg * 8;

  for (int tt = 0; tt < TILES; ++tt) {
    int tile = z * TILES + tt, j0 = tile * 32;
    __syncthreads();
    uint4 rbh = *(const uint4*)(hhp + j0);
    uint4 rbl = *(const uint4*)(hlp + j0);
    if (t < 32) est[t] = es[(size_t)(j0 + t) * H + hh];
    if (t >= 64 && t < 128) mword[t - 64] = bits[(size_t)(R0 + t - 64) * NW + tile];
    __syncthreads();
    *(uint4*)&BhS[sc * LW + sjo] = rbh;
    *(uint4*)&BlS[sc * LW + sjo] = rbl;
    {
      unsigned wbits = mword[rr];
      int selfj = (R0 + rr) - j0;
      if (selfj >= 0 && selfj < 32) wbits |= (1u << selfj);
      float edv = edl[rr], mv = ml[rr];
      float w[8], wlo[8];
      #pragma unroll
      for (int q = 0; q < 8; ++q) {
        int jj = jr * 8 + q;
        float v = 0.f;
        if (wbits & (1u << jj)) v = exp2f(leaky02(edv + est[jj]) - mv);
        w[q] = v;
        spart += v;
        wlo[q] = v - hi_part(v);
      }
      uint4 uh, ul;
      uh.x = pack_h(w[0], w[1]); uh.y = pack_h(w[2], w[3]);
      uh.z = pack_h(w[4], w[5]); uh.w = pack_h(w[6], w[7]);
      ul.x = pack_h(wlo[0], wlo[1]); ul.y = pack_h(wlo[2], wlo[3]);
      ul.z = pack_h(wlo[4], wlo[5]); ul.w = pack_h(wlo[6], wlo[7]);
      *(uint4*)&WhS[rr * LW + jr * 8] = uh;
      *(uint4*)&WlS[rr * LW + jr * 8] = ul;
    }
    __syncthreads();
    short8v Ah = *(const short8v*)&WhS[aoff];
    short8v Al = *(const short8v*)&WlS[aoff];
    #pragma unroll
    for (int nf = 0; nf < 4; ++nf) {
      short8v bh = *(const short8v*)&BhS[(nf * 16 + arow) * LW + kg * 8];
      short8v bl = *(const short8v*)&BlS[(nf * 16 + arow) * LW + kg * 8];
      acc[nf] = __builtin_amdgcn_mfma_f32_16x16x32_bf16(Ah, bh, acc[nf], 0, 0, 0);
      acc[nf] = __builtin_amdgcn_mfma_f32_16x16x32_bf16(Ah, bl, acc[nf], 0, 0, 0);
      acc[nf] = __builtin_amdgcn_mfma_f32_16x16x32_bf16(Al, bh, acc[nf], 0, 0, 0);
    }
  }
  __syncthreads();
  sred[jr][rr] = spart;
  __syncthreads();
  if (t < 64)
    pden[((size_t)z * NN + R0 + t) * H + hh] =
        sred[0][t] + sred[1][t] + sred[2][t] + sred[3][t];
  #pragma unroll
  for (int nf = 0; nf < 4; ++nf) {
    #pragma unroll
    for (int r = 0; r < 4; ++r) {
      int row = R0 + wid * 16 + kg * 4 + r;
      int c = hh * 64 + nf * 16 + arow;
      pacc[((size_t)z * NN + row) * CS + c] = acc[nf][r];
    }
  }
}

template<int H, int ACT, int JS>
__global__ __launch_bounds__(256) void k_gat_dense_red(const float* __restrict__ pacc,
                                                       const float* __restrict__ pden,
                                                       const float* __restrict__ bias,
                                                       float* __restrict__ out) {
  constexpr int CS = H * 64;
  int idx = blockIdx.x * 256 + threadIdx.x;
  if (idx >= NN * CS) return;
  int row = idx / CS, c = idx - row * CS, hh = c >> 6;
  float a = 0.f, d = 0.f;
  #pragma unroll
  for (int z = 0; z < JS; ++z) a += pacc[((size_t)z * NN + row) * CS + c];
  #pragma unroll
  for (int z = 0; z < JS; ++z) d += pden[((size_t)z * NN + row) * H + hh];
  out[idx] = act_apply<ACT>(a / d + bias[c]);
}

// ---------------- dense GAT direct fp32 (ws fallback) ----------------
template<int H, int ACT>
__global__ __launch_bounds__(256) void k_gat_dense(const float* __restrict__ hsrc,
                                                   const float* __restrict__ es,
                                                   const float* __restrict__ ed,
                                                   const float* __restrict__ gm,
                                                   const unsigned* __restrict__ bits,
                                                   const float* __restrict__ bias,
                                                   float* __restrict__ out) {
  constexpr int CS = H * 64;
  __shared__ float htile[32][68];
  __shared__ float wl[32][68];
  __shared__ float est[32];
  __shared__ unsigned mword[64];
  __shared__ float edl[64], ml[64];
  __shared__ float sred[4][64];
  int R0 = blockIdx.x * 64;
  int hh = blockIdx.y;
  int t = threadIdx.x;
  int rg = t >> 4, dg = t & 15;
  int rr = t & 63, jr = t >> 6;
  float acc[4][4] = {{0.f}};
  float spart = 0.f;
  if (t < 64) {
    float e = ed[(size_t)(R0 + t) * H + hh];
    edl[t] = e;
    ml[t] = leaky02(e + gm[hh]);
  }
  __syncthreads();
  for (int tile = 0; tile < NN / 32; ++tile) {
    int j0 = tile * 32;
    {
      int jj = t >> 3, cq = (t & 7) * 8;
      const float* hp = hsrc + (size_t)(j0 + jj) * CS + hh * 64 + cq;
      *(float4*)&htile[jj][cq]     = *(const float4*)hp;
      *(float4*)&htile[jj][cq + 4] = *(const float4*)(hp + 4);
    }
    if (t < 32) est[t] = es[(size_t)(j0 + t) * H + hh];
    if (t >= 64 && t < 128) mword[t - 64] = bits[(size_t)(R0 + t - 64) * NW + tile];
    __syncthreads();
    {
      unsigned wbits = mword[rr];
      int selfj = (R0 + rr) - j0;
      if (selfj >= 0 && selfj < 32) wbits |= (1u << selfj);
      float edv = edl[rr], mv = ml[rr];
      #pragma unroll
      for (int q = 0; q < 8; ++q) {
        int jj = (q << 2) | jr;
        float w = 0.f;
        if (wbits & (1u << jj)) {
          w = exp2f(leaky02(edv + est[jj]) - mv);
        }
        wl[jj][rr] = w;
        spart += w;
      }
    }
    __syncthreads();
    #pragma unroll 8
    for (int jj = 0; jj < 32; ++jj) {
      float4 av = *(const float4*)&wl[jj][rg * 4];
      float4 bv = *(const float4*)&htile[jj][dg * 4];
      float ar[4] = {av.x, av.y, av.z, av.w};
      float br[4] = {bv.x, bv.y, bv.z, bv.w};
      #pragma unroll
      for (int ri = 0; ri < 4; ++ri)
        #pragma unroll
        for (int ci = 0; ci < 4; ++ci)
          acc[ri][ci] += ar[ri] * br[ci];
    }
    __syncthreads();
  }
  sred[jr][rr] = spart;
  __syncthreads();
  if (t < 64) ml[t] = sred[0][t] + sred[1][t] + sred[2][t] + sred[3][t];
  __syncthreads();
  int cbase = hh * 64 + dg * 4;
  float bv0 = bias[cbase], bv1 = bias[cbase + 1], bv2 = bias[cbase + 2], bv3 = bias[cbase + 3];
  for (int ri = 0; ri < 4; ++ri) {
    int r = rg * 4 + ri;
    float inv = 1.0f / ml[r];
    float4 o;
    o.x = act_apply<ACT>(acc[ri][0] * inv + bv0);
    o.y = act_apply<ACT>(acc[ri][1] * inv + bv1);
    o.z = act_apply<ACT>(acc[ri][2] * inv + bv2);
    o.w = act_apply<ACT>(acc[ri][3] * inv + bv3);
    *(float4*)&out[(size_t)(R0 + r) * CS + cbase] = o;
  }
}

// ---------------- GCN via dense masked MFMA ----------------
template<int JS>
__global__ __launch_bounds__(256) void k_gcn_mfma(
    const ushort_t* __restrict__ bhT,
    const ushort_t* __restrict__ blT,
    const unsigned* __restrict__ b0,
    const unsigned* __restrict__ b1,
    float* __restrict__ pacc,
    int zRows, int rowOffY, int colOffY, int cStride) {
  constexpr int TILES = (NN / 32) / JS;
  constexpr int LW = 40;
  __shared__ ushort_t BhS[128 * LW], BlS[128 * LW];
  __shared__ unsigned mword[64];
  int R0 = blockIdx.x * 64, y = blockIdx.y, z = blockIdx.z;
  const unsigned* bits = y ? b1 : b0;
  int t = threadIdx.x;
  int wid = t >> 6, lane = t & 63;
  int arow = lane & 15, kg = lane >> 4;
  int sc = t >> 1, jh = (t & 1) * 16;
  const ushort_t* bhp = bhT + ((size_t)y * 128 + sc) * NN + jh;
  const ushort_t* blp = blT + ((size_t)y * 128 + sc) * NN + jh;
  f32x4v acc[4][2];
  #pragma unroll
  for (int rf = 0; rf < 4; ++rf)
    #pragma unroll
    for (int cf = 0; cf < 2; ++cf) acc[rf][cf] = (f32x4v){0.f, 0.f, 0.f, 0.f};

  for (int tt = 0; tt < TILES; ++tt) {
    int tile = z * TILES + tt, j0 = tile * 32;
    uint4 h0 = *(const uint4*)(bhp + j0);
    uint4 h1 = *(const uint4*)(bhp + j0 + 8);
    uint4 l0 = *(const uint4*)(blp + j0);
    uint4 l1 = *(const uint4*)(blp + j0 + 8);
    __syncthreads();
    *(uint4*)&BhS[sc * LW + jh]     = h0;
    *(uint4*)&BhS[sc * LW + jh + 8] = h1;
    *(uint4*)&BlS[sc * LW + jh]     = l0;
    *(uint4*)&BlS[sc * LW + jh + 8] = l1;
    if (t < 64) mword[t] = bits[(size_t)(R0 + t) * NW + tile];
    __syncthreads();
    short8v Aw[4];
    #pragma unroll
    for (int rf = 0; rf < 4; ++rf) {
      unsigned wb = mword[rf * 16 + arow];
      unsigned oct = (wb >> (kg * 8)) & 0xffu;
      #pragma unroll
      for (int q = 0; q < 8; ++q)
        Aw[rf][q] = (short)(((oct >> q) & 1u) ? 0x3f80 : 0);
    }
    #pragma unroll
    for (int cf = 0; cf < 2; ++cf) {
      int col = wid * 32 + cf * 16 + arow;
      short8v bh = *(const short8v*)&BhS[col * LW + kg * 8];
      short8v bl = *(const short8v*)&BlS[col * LW + kg * 8];
      #pragma unroll
      for (int rf = 0; rf < 4; ++rf) {
        acc[rf][cf] = __builtin_amdgcn_mfma_f32_16x16x32_bf16(Aw[rf], bh, acc[rf][cf], 0, 0, 0);
        acc[rf][cf] = __builtin_amdgcn_mfma_f32_16x16x32_bf16(Aw[rf], bl, acc[rf][cf], 0, 0, 0);
      }
    }
  }
  #pragma unroll
  for (int rf = 0; rf < 4; ++rf)
    #pragma unroll
    for (int cf = 0; cf < 2; ++cf)
      #pragma unroll
      for (int r = 0; r < 4; ++r) {
        int row = R0 + rf * 16 + kg * 4 + r;
        int c = wid * 32 + cf * 16 + arow;
        pacc[((size_t)z * zRows + (size_t)y * rowOffY + row) * cStride + y * colOffY + c] =
            acc[rf][cf][r];
      }
}

template<int JS>
__global__ __launch_bounds__(256) void k_gcn_red(const float* __restrict__ pacc,
                                                 const float* __restrict__ xw,
                                                 const float* __restrict__ d0,
                                                 const float* __restrict__ d1,
                                                 const float* __restrict__ bias,
                                                 float* __restrict__ out,
                                                 int rowsTotal, int C) {
  int idx = blockIdx.x * 256 + threadIdx.x;
  if (idx >= rowsTotal * C) return;
  int blk = idx / C, c = idx - blk * C;
  float s = 0.f;
  #pragma unroll
  for (int z = 0; z < JS; ++z) s += pacc[((size_t)z * rowsTotal + blk) * C + c];
  int i = blk >= NN ? blk - NN : blk;
  float di = (blk >= NN ? d1 : d0)[i];
  float v = di * (s + di * xw[(size_t)blk * C + c]) + bias[c];
  out[idx] = fmaxf(v, 0.f);
}

// ---------------- sparse GCN convs (ws fallback) ----------------
__global__ __launch_bounds__(256) void k_gcn256(const float* __restrict__ xw,
                                                const unsigned* __restrict__ bits,
                                                const float* __restrict__ dinv,
                                                const float* __restrict__ bias,
                                                float* __restrict__ out) {
  __shared__ unsigned rowb[NW];
  __shared__ unsigned jlist[512];
  __shared__ int cnt;
  int i = blockIdx.x, t = threadIdx.x;
  if (t < NW) rowb[t] = bits[(size_t)i * NW + t];
  float acc = 0.f;
  __syncthreads();
  for (int p = 0; p < 6; ++p) {
    __syncthreads();
    int cN = enum_bits16(rowb, p, jlist, &cnt, t);
    for (int idx = 0; idx < cN; ++idx) {
      int j = (int)jlist[idx];
      acc += dinv[j] * xw[(size_t)j * 256 + t];
    }
  }
  float di = dinv[i];
  float v = di * (acc + di * xw[(size_t)i * 256 + t]) + bias[t];
  out[(size_t)i * 256 + t] = fmaxf(v, 0.f);
}

__global__ __launch_bounds__(256) void k_gcn128b(const float* __restrict__ xw,
                                                 const unsigned* __restrict__ b0,
                                                 const unsigned* __restrict__ b1,
                                                 const float* __restrict__ d0,
                                                 const float* __restrict__ d1,
                                                 const float* __restrict__ bias,
                                                 float* __restrict__ outb) {
  __shared__ unsigned rowb[NW];
  __shared__ unsigned jlist[512];
  __shared__ int cnt;
  __shared__ float red[256];
  int blk = blockIdx.x, t = threadIdx.x;
  int br = blk >= NN;
  int i = br ? blk - NN : blk;
  const unsigned* bits = br ? b1 : b0;
  const float* dinv = br ? d1 : d0;
  const float* xb = xw + (size_t)br * NN * 128;
  if (t < NW) rowb[t] = bits[(size_t)i * NW + t];
  int g = t >> 7, c = t & 127;
  float acc = 0.f;
  __syncthreads();
  for (int p = 0; p < 6; ++p) {
    __syncthreads();
    int cN = enum_bits16(rowb, p, jlist, &cnt, t);
    for (int idx = g; idx < cN; idx += 2) {
      int j = (int)jlist[idx];
      acc += dinv[j] * xb[(size_t)j * 128 + c];
    }
  }
  __syncthreads();
  red[t] = acc;
  __syncthreads();
  if (t < 128) {
    acc = red[t] + red[t + 128];
    float di = dinv[i];
    float v = di * (acc + di * xb[(size_t)i * 128 + c]) + bias[c];
    outb[(size_t)blk * 128 + c] = fmaxf(v, 0.f);
  }
}

// ---------------- fusion kernels ----------------
__global__ __launch_bounds__(256) void k_highway(const float* __restrict__ aa,
                                                 const float* __restrict__ bb,
                                                 float* __restrict__ hh) {
  int idx = blockIdx.x * 256 + threadIdx.x;
  if (idx < NN * 64) {
    float a = aa[idx], b = bb[idx];
    float z = sigm(a + b);
    hh[idx] = z * b + (1.f - z) * a;
  }
}

__global__ __launch_bounds__(256) void k_gru(const float* __restrict__ gx,
                                             const float* __restrict__ gh,
                                             const float* __restrict__ hh,
                                             float* __restrict__ cc) {
  int idx = blockIdx.x * 256 + threadIdx.x;
  if (idx < NN * 64) {
    int i = idx >> 6, d = idx & 63;
    float xr = gx[(size_t)i * 192 + d];
    float xz = gx[(size_t)i * 192 + 64 + d];
    float xn = gx[(size_t)i * 192 + 128 + d];
    float hr = gh[(size_t)i * 192 + d];
    float hz = gh[(size_t)i * 192 + 64 + d];
    float hn = gh[(size_t)i * 192 + 128 + d];
    float r = sigm(xr + hr);
    float z = sigm(xz + hz);
    float n = tanhf(xn + r * hn);
    cc[idx] = (1.f - z) * n + z * hh[idx];
  }
}

__global__ __launch_bounds__(64) void k_pool(const float* __restrict__ cc,
                                             const int* __restrict__ atoms,
                                             const int* __restrict__ resl,
                                             float* __restrict__ vi) {
  int s = blockIdx.x, lane = threadIdx.x;
  int start = 0;
  for (int k = 0; k < s; ++k) start += atoms[k] + resl[k];
  int end = start + atoms[s] + resl[s];
  if (end > NN) end = NN;
  float m = -3.0e38f;
  for (int r = start; r < end; ++r) m = fmaxf(m, cc[(size_t)r * 64 + lane]);
  vi[s * 64 + lane] = m;
}

__global__ __launch_bounds__(256) void k_final(const float* __restrict__ vi,
                                               const float* __restrict__ tAW,
                                               const float* __restrict__ tAb,
                                               const float* __restrict__ tBW,
                                               const float* __restrict__ tBb,
                                               float* __restrict__ out) {
  __shared__ float v[NB * 64];
  __shared__ float t1[NB * 128];
  int t = threadIdx.x;
  for (int idx = t; idx < NB * 64; idx += 256) v[idx] = vi[idx];
  __syncthreads();
  for (int idx = t; idx < NB * 128; idx += 256) {
    int r = idx >> 7, c = idx & 127;
    float a = tAb[c];
    for (int k = 0; k < 64; ++k) a += v[r * 64 + k] * tAW[k * 128 + c];
    t1[idx] = fmaxf(a, 0.f);
  }
  __syncthreads();
  for (int idx = t; idx < NB * 120; idx += 256) {
    int r = idx / 120, c = idx % 120;
    float a = tBb[c];
    for (int k = 0; k < 128; ++k) a += t1[r * 128 + k] * tBW[k * 120 + c];
    out[idx] = a;
  }
}

} // anonymous namespace

extern "C" void kernel_launch(void* const* d_in, const int* in_sizes, int n_in,
                              void* d_out, int out_size, void* d_ws, size_t ws_size,
                              hipStream_t stream) {
  (void)in_sizes; (void)n_in; (void)out_size;
  const float* x     = (const float*)d_in[0];
  const float* g1_W  = (const float*)d_in[2];
  const float* g1_as = (const float*)d_in[3];
  const float* g1_ad = (const float*)d_in[4];
  const float* g1_b  = (const float*)d_in[5];
  const float* g2_W  = (const float*)d_in[6];
  const float* g2_as = (const float*)d_in[7];
  const float* g2_ad = (const float*)d_in[8];
  const float* g2_b  = (const float*)d_in[9];
  const float* gA_W  = (const float*)d_in[10];
  const float* gA_b  = (const float*)d_in[11];
  const float* gB_W  = (const float*)d_in[12];
  const float* gB_b  = (const float*)d_in[13];
  const float* gC_W  = (const float*)d_in[14];
  const float* gC_b  = (const float*)d_in[15];
  const float* c2_W  = (const float*)d_in[16];
  const float* c2_b  = (const float*)d_in[17];
  const float* c3_W  = (const float*)d_in[18];
  const float* c3_b  = (const float*)d_in[19];
  const float* hwA_W = (const float*)d_in[20];
  const float* hwA_b = (const float*)d_in[21];
  const float* hwB_W = (const float*)d_in[22];
  const float* hwB_b = (const float*)d_in[23];
  const float* gWih  = (const float*)d_in[24];
  const float* gWhh  = (const float*)d_in[25];
  const float* gbih  = (const float*)d_in[26];
  const float* gbhh  = (const float*)d_in[27];
  const float* tA_W  = (const float*)d_in[28];
  const float* tA_b  = (const float*)d_in[29];
  const float* tB_W  = (const float*)d_in[30];
  const float* tB_b  = (const float*)d_in[31];
  const int* edges   = (const int*)d_in[32];
  const int* atoms   = (const int*)d_in[33];
  const int* resl    = (const int*)d_in[34];
  float* out = (float*)d_out;

  // ---- workspace carve ----
  unsigned* bitsA  = (unsigned*)d_ws;
  unsigned* bitsA2 = bitsA + (size_t)NN * NW;
  unsigned* bitsA3 = bitsA2 + (size_t)NN * NW;
  float* fp = (float*)(bitsA3 + (size_t)NN * NW);
  float* dinvA  = fp; fp += NN;
  float* dinvA2 = fp; fp += NN;
  float* HB     = fp; fp += (size_t)NN * 512;
  float* ES1    = fp; fp += (size_t)NN * 8;
  float* ED1    = fp; fp += (size_t)NN * 8;
  float* GM1    = fp; fp += 16;
  float* V1ALL  = fp; fp += (size_t)3 * NN * 512;   // GAT1 out, branch-major
  float* H2BALL = fp; fp += (size_t)3 * NN * 64;
  float* ES2ALL = fp; fp += (size_t)3 * NN;
  float* ED2ALL = fp; fp += (size_t)3 * NN;
  float* GM2ALL = fp; fp += 16;
  float* V2ALL  = fp; fp += (size_t)3 * NN * 64;
  float* V3ALL  = fp; fp += (size_t)3 * NN * 64;
  float* V4ALL  = fp; fp += (size_t)3 * NN * 128;
  float* V5ALL  = fp; fp += (size_t)3 * NN * 64;    // branch3 slice = H3F
  float* XC2    = fp; fp += (size_t)2 * NN * 128;
  float* TG     = fp; fp += (size_t)2 * NN * 128;   // GCN1 out (br1: T1, br2: H2F)
  float* XC3    = fp; fp += (size_t)NN * 256;
  float* H1F    = fp; fp += (size_t)NN * 256;
  float* AAb    = fp; fp += (size_t)NN * 64;
  float* BBb    = fp; fp += (size_t)NN * 64;
  float* HHb    = fp; fp += (size_t)NN * 64;
  float* VI     = fp; fp += NB * 64;
  // aliases on V1ALL (dead after the g2 batched gemm)
  float* GX = V1ALL;
  float* GH = V1ALL + (size_t)NN * 192;
  float* CC = V1ALL + (size_t)NN * 384;
  // split-bf16 + partial buffers
  char* cp = (char*)fp;
  ushort_t* HhT8 = (ushort_t*)cp; cp += (size_t)512 * NN * 2;
  ushort_t* HlT8 = (ushort_t*)cp; cp += (size_t)512 * NN * 2;
  ushort_t* HhT1 = (ushort_t*)cp; cp += (size_t)64 * NN * 2;
  ushort_t* HlT1 = (ushort_t*)cp; cp += (size_t)64 * NN * 2;
  ushort_t* XWSH = (ushort_t*)cp; cp += (size_t)256 * NN * 2;
  ushort_t* XWSL = (ushort_t*)cp; cp += (size_t)256 * NN * 2;
  float* PACC = (float*)cp; cp += (size_t)4 * NN * 512 * 4;   // reused by all partial passes
  float* PDEN = (float*)cp; cp += (size_t)16 * NN * 8 * 4;
  int mode = ((size_t)(cp - (char*)d_ws) <= ws_size) ? 1 : 0;

  float* H3F = V5ALL + (size_t)2 * NN * 64;
  float* H2F = TG + (size_t)NN * 128;

  // ---- adjacency ----
  hipMemsetAsync(bitsA, 0, (size_t)NN * NW * sizeof(unsigned), stream);
  k_scatter<<<(NEDGE_C + 255) / 256, 256, 0, stream>>>(edges, bitsA);
  k_bmm<<<NN, 128, 0, stream>>>(bitsA, bitsA, bitsA2);
  k_bmm<<<NN, 128, 0, stream>>>(bitsA, bitsA2, bitsA3);
  k_dinv<<<NN / 256, 256, 0, stream>>>(bitsA, dinvA);
  k_dinv<<<NN / 256, 256, 0, stream>>>(bitsA2, dinvA2);

  // ---- shared GAT1 input ----
  k_gemm<0><<<dim3(48, 8), 256, 0, stream>>>(x, g1_W, nullptr, HB, 64, 512);
  k_scores<8><<<NN, 64, 0, stream>>>(HB, g1_as, g1_ad, ES1, ED1);
  k_gmax8<<<1, 256, 0, stream>>>(ES1, GM1);

  // ---- GAT1 for all 3 branches -> V1ALL ----
  if (mode) {
    k_gat_sparse8_part<4><<<dim3(NN, 4), 256, 0, stream>>>(HB, ES1, ED1, GM1, bitsA, PACC, PDEN);
    k_gat_dense_red<8, 2, 4><<<NN * 512 / 256, 256, 0, stream>>>(PACC, PDEN, g1_b, V1ALL);
    k_gat_sparse8_part<4><<<dim3(NN, 4), 256, 0, stream>>>(HB, ES1, ED1, GM1, bitsA2, PACC, PDEN);
    k_gat_dense_red<8, 2, 4><<<NN * 512 / 256, 256, 0, stream>>>(PACC, PDEN, g1_b, V1ALL + (size_t)NN * 512);
    k_split_xws<<<dim3(48, 8), 256, 0, stream>>>(HB, 512, nullptr, HhT8, HlT8);
    k_gat_dense_mfma<8, 4><<<dim3(48, 8, 4), 256, 0, stream>>>(HhT8, HlT8, ES1, ED1, GM1, bitsA3, PACC, PDEN);
    k_gat_dense_red<8, 2, 4><<<NN * 512 / 256, 256, 0, stream>>>(PACC, PDEN, g1_b, V1ALL + (size_t)2 * NN * 512);
  } else {
    k_gat_sparse8<2><<<NN, 256, 0, stream>>>(HB, ES1, ED1, GM1, bitsA, g1_b, V1ALL);
    k_gat_sparse8<2><<<NN, 256, 0, stream>>>(HB, ES1, ED1, GM1, bitsA2, g1_b, V1ALL + (size_t)NN * 512);
    k_gat_dense<8, 2><<<dim3(48, 8), 256, 0, stream>>>(HB, ES1, ED1, GM1, bitsA3, g1_b, V1ALL + (size_t)2 * NN * 512);
  }

  // ---- batched GAT2 prologue ----
  k_gemm<0><<<dim3(144, 1), 256, 0, stream>>>(V1ALL, g2_W, nullptr, H2BALL, 512, 64);
  k_scores<1><<<3 * NN, 64, 0, stream>>>(H2BALL, g2_as, g2_ad, ES2ALL, ED2ALL);
  k_gmax1b<<<3, 256, 0, stream>>>(ES2ALL, GM2ALL);

  // ---- GAT2 per branch -> V2ALL ----
  k_gat_sparse1<1><<<NN, 256, 0, stream>>>(H2BALL, ES2ALL, ED2ALL, GM2ALL, bitsA, g2_b, V2ALL);
  k_gat_sparse1<1><<<NN, 256, 0, stream>>>(H2BALL + (size_t)NN * 64, ES2ALL + NN, ED2ALL + NN,
                                           GM2ALL + 1, bitsA2, g2_b, V2ALL + (size_t)NN * 64);
  if (mode) {
    k_split_xws<<<dim3(48, 1), 256, 0, stream>>>(H2BALL + (size_t)2 * NN * 64, 64, nullptr, HhT1, HlT1);
    k_gat_dense_mfma<1, 16><<<dim3(48, 1, 16), 256, 0, stream>>>(
        HhT1, HlT1, ES2ALL + 2 * NN, ED2ALL + 2 * NN, GM2ALL + 2, bitsA3, PACC, PDEN);
    k_gat_dense_red<1, 1, 16><<<NN * 64 / 256, 256, 0, stream>>>(PACC, PDEN, g2_b, V2ALL + (size_t)2 * NN * 64);
  } else {
    k_gat_dense<1, 1><<<dim3(48, 1), 256, 0, stream>>>(
        H2BALL + (size_t)2 * NN * 64, ES2ALL + 2 * NN, ED2ALL + 2 * NN, GM2ALL + 2, bitsA3, g2_b,
        V2ALL + (size_t)2 * NN * 64);
  }

  // ---- batched branch tails ----
  k_gemm<1><<<dim3(144, 1), 256, 0, stream>>>(V2ALL, gA_W, gA_b, V3ALL, 64, 64);
  k_gemm<1><<<dim3(144, 2), 256, 0, stream>>>(V3ALL, gB_W, gB_b, V4ALL, 64, 128);
  k_gemm<1><<<dim3(144, 1), 256, 0, stream>>>(V4ALL, gC_W, gC_b, V5ALL, 128, 64);

  // ---- GCN chains (branches 1+2 batched) ----
  k_gemm<0><<<dim3(96, 2), 256, 0, stream>>>(V5ALL, c2_W, nullptr, XC2, 64, 128);
  if (mode) {
    k_split_xws<<<dim3(48, 2), 256, 0, stream>>>(XC2, 128, dinvA, XWSH, XWSL);
    k_split_xws<<<dim3(48, 2), 256, 0, stream>>>(XC2 + (size_t)NN * 128, 128, dinvA2,
                                                 XWSH + (size_t)128 * NN, XWSL + (size_t)128 * NN);
    k_gcn_mfma<8><<<dim3(48, 2, 8), 256, 0, stream>>>(XWSH, XWSL, bitsA, bitsA2, PACC, 2 * NN, NN, 0, 128);
    k_gcn_red<8><<<2 * NN * 128 / 256, 256, 0, stream>>>(PACC, XC2, dinvA, dinvA2, c2_b, TG, 2 * NN, 128);
  } else {
    k_gcn128b<<<2 * NN, 256, 0, stream>>>(XC2, bitsA, bitsA2, dinvA, dinvA2, c2_b, TG);
  }
  k_gemm<0><<<dim3(48, 4), 256, 0, stream>>>(TG, c3_W, nullptr, XC3, 128, 256);
  if (mode) {
    k_split_xws<<<dim3(48, 4), 256, 0, stream>>>(XC3, 256, dinvA, XWSH, XWSL);
    k_gcn_mfma<8><<<dim3(48, 2, 8), 256, 0, stream>>>(XWSH, XWSL, bitsA, bitsA, PACC, NN, 0, 128, 256);
    k_gcn_red<8><<<NN * 256 / 256, 256, 0, stream>>>(PACC, XC3, dinvA, dinvA, c3_b, H1F, NN, 256);
  } else {
    k_gcn256<<<NN, 256, 0, stream>>>(XC3, bitsA, dinvA, c3_b, H1F);
  }

  // ---- highway + GRU + pool + head ----
  k_gemm<0><<<dim3(48, 1), 256, 0, stream>>>(H1F, hwA_W, hwA_b, AAb, 256, 64);
  k_gemm<0><<<dim3(48, 1), 256, 0, stream>>>(H2F, hwB_W, hwB_b, BBb, 128, 64);
  k_highway<<<NN * 64 / 256, 256, 0, stream>>>(AAb, BBb, HHb);
  k_gemm<0><<<dim3(48, 3), 256, 0, stream>>>(H3F, gWih, gbih, GX, 64, 192);
  k_gemm<0><<<dim3(48, 3), 256, 0, stream>>>(HHb, gWhh, gbhh, GH, 64, 192);
  k_gru<<<NN * 64 / 256, 256, 0, stream>>>(GX, GH, HHb, CC);
  k_pool<<<NB, 64, 0, stream>>>(CC, atoms, resl, VI);
  k_final<<<1, 256, 0, stream>>>(VI, tA_W, tA_b, tB_W, tB_b, out);
}